// Round 3
// baseline (505.021 us; speedup 1.0000x reference)
//
#include <hip/hip_runtime.h>
#include <math.h>

constexpr int cB  = 256;
constexpr int cI  = 512;
constexpr int cR  = 512;
constexpr int cA  = 196;
constexpr int cV  = 10000;
constexpr int cH4 = 2048;   // 4*R

typedef short bf16x8 __attribute__((ext_vector_type(8)));
typedef float f32x4  __attribute__((ext_vector_type(4)));
typedef unsigned short us8 __attribute__((ext_vector_type(8)));

__device__ inline unsigned short f2bf(float f) {
    unsigned int u = __float_as_uint(f);
    u += 0x7fffu + ((u >> 16) & 1u);
    return (unsigned short)(u >> 16);
}
__device__ inline float bf2f(unsigned short s) {
    return __uint_as_float(((unsigned int)s) << 16);
}
// fast tanh: 1 - 2/(1+e^{2x}); exact at +-inf, ~1e-7 rel err, ~5 VALU ops
__device__ inline float tanh_f(float x) {
    return 1.f - 2.f / (1.f + __expf(2.f * x));
}

// ---------------------------------------------------------------------------
// k_cvt4: four fp32->bf16 conversions in one launch.
// ---------------------------------------------------------------------------
__global__ __launch_bounds__(256) void k_cvt4(
    const float* __restrict__ s0, unsigned short* __restrict__ d0, int nb0,
    const float* __restrict__ s1, unsigned short* __restrict__ d1, int nb1,
    const float* __restrict__ s2, unsigned short* __restrict__ d2, int nb2,
    const float* __restrict__ s3, unsigned short* __restrict__ d3, int nb3)
{
    int blk = blockIdx.x;
    const float* src; unsigned short* dst; int base;
    if (blk < nb0)                  { src = s0; dst = d0; base = blk; }
    else if (blk < nb0 + nb1)       { src = s1; dst = d1; base = blk - nb0; }
    else if (blk < nb0 + nb1 + nb2) { src = s2; dst = d2; base = blk - nb0 - nb1; }
    else                            { src = s3; dst = d3; base = blk - nb0 - nb1 - nb2; }
    int i = base * 256 + threadIdx.x;
    float4 v = ((const float4*)src)[i];
    ushort4 b;
    b.x = f2bf(v.x); b.y = f2bf(v.y); b.z = f2bf(v.z); b.w = f2bf(v.w);
    ((ushort4*)dst)[i] = b;
}

// ---------------------------------------------------------------------------
// k_ah: out[b,o] = bias[o] + sum_k h[b,k] * W[o,k]   (o < cA)  fp32
// ---------------------------------------------------------------------------
__global__ __launch_bounds__(256) void k_ah(
    const float* __restrict__ h, const float* __restrict__ W,
    const float* __restrict__ bias, float* __restrict__ out)
{
    __shared__ __align__(16) float h_s[cR];
    int b = blockIdx.x;
    int t = threadIdx.x;
    h_s[t]       = h[b * cR + t];
    h_s[t + 256] = h[b * cR + t + 256];
    __syncthreads();
    if (t < cA) {
        const float4* Wv = (const float4*)(W + (size_t)t * cR);
        const float4* hv = (const float4*)h_s;
        float acc = 0.f;
        #pragma unroll 4
        for (int k = 0; k < cR / 4; ++k) {
            float4 w4 = Wv[k], x4 = hv[k];
            acc += w4.x * x4.x + w4.y * x4.y + w4.z * x4.z + w4.w * x4.w;
        }
        out[b * cA + t] = acc + bias[t];
    }
}

// ---------------------------------------------------------------------------
// ROUND-3 RESTRUCTURE: fused attend. Rounds 0-2 showed the scores GEMM is
// pinned by TOTAL traffic (~1.5-2 TB/s effective for this mix), independent of
// access pattern/occupancy. So: move fewer bytes. One block owns 49 att rows
// of ONE b (A=196=4x49), stages them bf16 in LDS ONCE, and does
// scores-GEMM + tanh.wd epilogue + unnormalized softmax + weighted-sum
// partial in a single pass (att never re-read). Cross-block softmax via
// (m, den, num[512]) partials + tiny combiner (exact rescale algebra).
// Kills k_attres' 51MB re-read per attend and 2 kernel launches.
// LDS: att 66.6K + wa 33.3K + red2 8K + misc ~2.5K = ~110KB -> 1 block/CU.
// ---------------------------------------------------------------------------
constexpr int SC_LDA = 72;    // bf16 elems per wa_s row in old kernels
constexpr int AT_LDA = 520;   // bf16 elems per full-K row (1040 B)

// common body via macro-free duplication: k_attf1 (fp32 att + writeback),
// k_attf2 (bf16 att).

__global__ __launch_bounds__(256, 1) void k_attf1(
    const float* __restrict__ att, unsigned short* __restrict__ att_bf,
    const unsigned short* __restrict__ wa_bf,
    const float* __restrict__ ba, const float* __restrict__ Wd,
    const float* __restrict__ bd, const float* __restrict__ ah,
    float* __restrict__ pnum, float* __restrict__ pm, float* __restrict__ pden)
{
    __shared__ __align__(16) unsigned short att_s[64][AT_LDA];
    __shared__ __align__(16) unsigned short wa_s[32][AT_LDA];
    __shared__ float ba_s[224];
    __shared__ float wd_s[224];
    __shared__ float s_sc[64];
    __shared__ float s_e[64];
    __shared__ float red2[4][512];

    int tid  = threadIdx.x;
    int wave = tid >> 6;
    int lane = tid & 63;
    int lx   = lane & 15;
    int quad = lane >> 4;
    int blk  = blockIdx.x;
    int b    = blk >> 2;
    int a0   = (blk & 3) * 49;
    size_t rowbase = (size_t)b * cA + a0;
    const float* abase = att + rowbase * cR;
    unsigned short* wbase = att_bf + rowbase * cR;
    float bd0 = bd[0];

    if (tid < 224) {
        ba_s[tid] = (tid < cA) ? ba[tid] : 0.f;
        wd_s[tid] = (tid < cA) ? Wd[tid] : 0.f;
    }

    // per-thread output rows (scores): row = wave*16 + quad*4 + reg
    float ahv[4];
    int arow = wave * 16 + quad * 4;
    #pragma unroll
    for (int reg = 0; reg < 4; ++reg) {
        int al = arow + reg;
        ahv[reg] = (al < 49) ? ah[b * cA + a0 + al] : 0.f;
    }

    // prefetch wa chunk 0 (rows 0..31, always valid)
    us8 pwa[8];
    #pragma unroll
    for (int i = 0; i < 8; ++i) {
        int u = tid + i * 256;
        pwa[i] = *(const us8*)(wa_bf + (size_t)(u >> 6) * cR + (u & 63) * 8);
    }

    // phase 1: att fp32 load (fully contiguous 200KB) -> cvt -> LDS + writeback
    #pragma unroll 8
    for (int i = 0; i < 24; ++i) {
        int u = tid + i * 256;
        float4 v = *(const float4*)(abase + (size_t)u * 4);
        ushort4 bv;
        bv.x = f2bf(v.x); bv.y = f2bf(v.y); bv.z = f2bf(v.z); bv.w = f2bf(v.w);
        *(ushort4*)&att_s[u >> 7][(u & 127) * 4] = bv;
        *(ushort4*)(wbase + (size_t)u * 4) = bv;
    }
    {
        int u = tid + 24 * 256;
        if (u < 49 * 128) {
            float4 v = *(const float4*)(abase + (size_t)u * 4);
            ushort4 bv;
            bv.x = f2bf(v.x); bv.y = f2bf(v.y); bv.z = f2bf(v.z); bv.w = f2bf(v.w);
            *(ushort4*)&att_s[u >> 7][(u & 127) * 4] = bv;
            *(ushort4*)(wbase + (size_t)u * 4) = bv;
        }
    }

    float part[4] = {0.f, 0.f, 0.f, 0.f};

    for (int ch = 0; ch < 7; ++ch) {
        #pragma unroll
        for (int i = 0; i < 8; ++i) {
            int u = tid + i * 256;
            *(us8*)&wa_s[u >> 6][(u & 63) * 8] = pwa[i];
        }
        if (ch < 6) {
            int c0n = (ch + 1) * 32;
            #pragma unroll
            for (int i = 0; i < 8; ++i) {
                int u = tid + i * 256;
                int r = c0n + (u >> 6);
                pwa[i] = (r < cA) ? *(const us8*)(wa_bf + (size_t)r * cR + (u & 63) * 8)
                                  : (us8){0,0,0,0,0,0,0,0};
            }
        }
        __syncthreads();

        f32x4 acc0 = {0.f,0.f,0.f,0.f}, acc1 = {0.f,0.f,0.f,0.f};
        #pragma unroll
        for (int ks = 0; ks < 16; ++ks) {
            int kb = ks * 32 + quad * 8;
            bf16x8 af = *(const bf16x8*)&att_s[wave * 16 + lx][kb];
            bf16x8 b0 = *(const bf16x8*)&wa_s[lx][kb];
            bf16x8 b1 = *(const bf16x8*)&wa_s[16 + lx][kb];
            acc0 = __builtin_amdgcn_mfma_f32_16x16x32_bf16(af, b0, acc0, 0, 0, 0);
            acc1 = __builtin_amdgcn_mfma_f32_16x16x32_bf16(af, b1, acc1, 0, 0, 0);
        }
        int c0 = ch * 32;
        #pragma unroll
        for (int reg = 0; reg < 4; ++reg) {
            part[reg] += tanh_f(acc0[reg] + ba_s[c0 + lx] + ahv[reg]) * wd_s[c0 + lx];
            part[reg] += tanh_f(acc1[reg] + ba_s[c0 + 16 + lx] + ahv[reg]) * wd_s[c0 + 16 + lx];
        }
        __syncthreads();
    }

    #pragma unroll
    for (int reg = 0; reg < 4; ++reg) {
        float p = part[reg];
        p += __shfl_xor(p, 1);
        p += __shfl_xor(p, 2);
        p += __shfl_xor(p, 4);
        p += __shfl_xor(p, 8);
        if (lx == 0) s_sc[wave * 16 + quad * 4 + reg] = p + bd0;
    }
    __syncthreads();

    // local softmax pieces over 49 rows
    float m = s_sc[0];
    #pragma unroll 8
    for (int a = 1; a < 49; ++a) m = fmaxf(m, s_sc[a]);
    if (tid < 49) s_e[tid] = __expf(s_sc[tid] - m);
    __syncthreads();
    float den = 0.f;
    #pragma unroll 8
    for (int a = 0; a < 49; ++a) den += s_e[a];

    // weighted-sum partial: num[512] = sum_a e_a * att[a,:]
    float num8[8] = {};
    for (int a = wave; a < 49; a += 4) {
        float e = s_e[a];
        us8 v = *(const us8*)&att_s[a][lane * 8];
        #pragma unroll
        for (int j = 0; j < 8; ++j)
            num8[j] += e * bf2f(v[j]);
    }
    #pragma unroll
    for (int j = 0; j < 8; ++j)
        red2[wave][lane * 8 + j] = num8[j];
    __syncthreads();
    #pragma unroll
    for (int rr = 0; rr < 2; ++rr) {
        int c = tid + rr * 256;
        pnum[(size_t)blk * cR + c] = red2[0][c] + red2[1][c] + red2[2][c] + red2[3][c];
    }
    if (tid == 0) { pm[blk] = m; pden[blk] = den; }
}

__global__ __launch_bounds__(256, 1) void k_attf2(
    const unsigned short* __restrict__ att_bf,
    const unsigned short* __restrict__ wa_bf,
    const float* __restrict__ ba, const float* __restrict__ Wd,
    const float* __restrict__ bd, const float* __restrict__ ah,
    float* __restrict__ pnum, float* __restrict__ pm, float* __restrict__ pden)
{
    __shared__ __align__(16) unsigned short att_s[64][AT_LDA];
    __shared__ __align__(16) unsigned short wa_s[32][AT_LDA];
    __shared__ float ba_s[224];
    __shared__ float wd_s[224];
    __shared__ float s_sc[64];
    __shared__ float s_e[64];
    __shared__ float red2[4][512];

    int tid  = threadIdx.x;
    int wave = tid >> 6;
    int lane = tid & 63;
    int lx   = lane & 15;
    int quad = lane >> 4;
    int blk  = blockIdx.x;
    int b    = blk >> 2;
    int a0   = (blk & 3) * 49;
    size_t rowbase = (size_t)b * cA + a0;
    const unsigned short* abase = att_bf + rowbase * cR;
    float bd0 = bd[0];

    if (tid < 224) {
        ba_s[tid] = (tid < cA) ? ba[tid] : 0.f;
        wd_s[tid] = (tid < cA) ? Wd[tid] : 0.f;
    }

    float ahv[4];
    int arow = wave * 16 + quad * 4;
    #pragma unroll
    for (int reg = 0; reg < 4; ++reg) {
        int al = arow + reg;
        ahv[reg] = (al < 49) ? ah[b * cA + a0 + al] : 0.f;
    }

    us8 pwa[8];
    #pragma unroll
    for (int i = 0; i < 8; ++i) {
        int u = tid + i * 256;
        pwa[i] = *(const us8*)(wa_bf + (size_t)(u >> 6) * cR + (u & 63) * 8);
    }

    // phase 1: att bf16 load (contiguous 100KB) -> LDS
    #pragma unroll 6
    for (int i = 0; i < 12; ++i) {
        int u = tid + i * 256;
        us8 v = *(const us8*)(abase + (size_t)u * 8);
        *(us8*)&att_s[u >> 6][(u & 63) * 8] = v;
    }
    {
        int u = tid + 12 * 256;
        if (u < 49 * 64) {
            us8 v = *(const us8*)(abase + (size_t)u * 8);
            *(us8*)&att_s[u >> 6][(u & 63) * 8] = v;
        }
    }

    float part[4] = {0.f, 0.f, 0.f, 0.f};

    for (int ch = 0; ch < 7; ++ch) {
        #pragma unroll
        for (int i = 0; i < 8; ++i) {
            int u = tid + i * 256;
            *(us8*)&wa_s[u >> 6][(u & 63) * 8] = pwa[i];
        }
        if (ch < 6) {
            int c0n = (ch + 1) * 32;
            #pragma unroll
            for (int i = 0; i < 8; ++i) {
                int u = tid + i * 256;
                int r = c0n + (u >> 6);
                pwa[i] = (r < cA) ? *(const us8*)(wa_bf + (size_t)r * cR + (u & 63) * 8)
                                  : (us8){0,0,0,0,0,0,0,0};
            }
        }
        __syncthreads();

        f32x4 acc0 = {0.f,0.f,0.f,0.f}, acc1 = {0.f,0.f,0.f,0.f};
        #pragma unroll
        for (int ks = 0; ks < 16; ++ks) {
            int kb = ks * 32 + quad * 8;
            bf16x8 af = *(const bf16x8*)&att_s[wave * 16 + lx][kb];
            bf16x8 b0 = *(const bf16x8*)&wa_s[lx][kb];
            bf16x8 b1 = *(const bf16x8*)&wa_s[16 + lx][kb];
            acc0 = __builtin_amdgcn_mfma_f32_16x16x32_bf16(af, b0, acc0, 0, 0, 0);
            acc1 = __builtin_amdgcn_mfma_f32_16x16x32_bf16(af, b1, acc1, 0, 0, 0);
        }
        int c0 = ch * 32;
        #pragma unroll
        for (int reg = 0; reg < 4; ++reg) {
            part[reg] += tanh_f(acc0[reg] + ba_s[c0 + lx] + ahv[reg]) * wd_s[c0 + lx];
            part[reg] += tanh_f(acc1[reg] + ba_s[c0 + 16 + lx] + ahv[reg]) * wd_s[c0 + 16 + lx];
        }
        __syncthreads();
    }

    #pragma unroll
    for (int reg = 0; reg < 4; ++reg) {
        float p = part[reg];
        p += __shfl_xor(p, 1);
        p += __shfl_xor(p, 2);
        p += __shfl_xor(p, 4);
        p += __shfl_xor(p, 8);
        if (lx == 0) s_sc[wave * 16 + quad * 4 + reg] = p + bd0;
    }
    __syncthreads();

    float m = s_sc[0];
    #pragma unroll 8
    for (int a = 1; a < 49; ++a) m = fmaxf(m, s_sc[a]);
    if (tid < 49) s_e[tid] = __expf(s_sc[tid] - m);
    __syncthreads();
    float den = 0.f;
    #pragma unroll 8
    for (int a = 0; a < 49; ++a) den += s_e[a];

    float num8[8] = {};
    for (int a = wave; a < 49; a += 4) {
        float e = s_e[a];
        us8 v = *(const us8*)&att_s[a][lane * 8];
        #pragma unroll
        for (int j = 0; j < 8; ++j)
            num8[j] += e * bf2f(v[j]);
    }
    #pragma unroll
    for (int j = 0; j < 8; ++j)
        red2[wave][lane * 8 + j] = num8[j];
    __syncthreads();
    #pragma unroll
    for (int rr = 0; rr < 2; ++rr) {
        int c = tid + rr * 256;
        pnum[(size_t)blk * cR + c] = red2[0][c] + red2[1][c] + red2[2][c] + red2[3][c];
    }
    if (tid == 0) { pm[blk] = m; pden[blk] = den; }
}

// ---------------------------------------------------------------------------
// k_attfin: combine 4 per-block softmax partials per b (exact rescale),
// optional addin, write fp32 + bf16.
// ---------------------------------------------------------------------------
__global__ __launch_bounds__(256) void k_attfin(
    const float* __restrict__ pnum, const float* __restrict__ pm,
    const float* __restrict__ pden, const float* __restrict__ addin,
    float* __restrict__ out, unsigned short* __restrict__ out_bf)
{
    int b = blockIdx.x, t = threadIdx.x;
    int base = b * 4;
    float m0 = pm[base], m1 = pm[base+1], m2 = pm[base+2], m3 = pm[base+3];
    float M = fmaxf(fmaxf(m0, m1), fmaxf(m2, m3));
    float w0 = __expf(m0 - M), w1 = __expf(m1 - M);
    float w2 = __expf(m2 - M), w3 = __expf(m3 - M);
    float D = w0 * pden[base] + w1 * pden[base+1] + w2 * pden[base+2] + w3 * pden[base+3];
    float inv = 1.f / D;
    #pragma unroll
    for (int rr = 0; rr < 2; ++rr) {
        int c = t + rr * 256;
        float s = w0 * pnum[(size_t)(base+0) * cR + c]
                + w1 * pnum[(size_t)(base+1) * cR + c]
                + w2 * pnum[(size_t)(base+2) * cR + c]
                + w3 * pnum[(size_t)(base+3) * cR + c];
        s *= inv;
        if (addin) s += addin[b * cR + c];
        out[b * cR + c] = s;
        out_bf[b * cR + c] = f2bf(s);
    }
}

// ---------------------------------------------------------------------------
// FALLBACK path kernels (small ws): round-1 M=64 scores + fp32 attres.
// ---------------------------------------------------------------------------
__global__ __launch_bounds__(256, 3) void k_scores_cv(
    const float* __restrict__ att, unsigned short* __restrict__ att_bf,
    const unsigned short* __restrict__ wa_bf,
    const float* __restrict__ ba, const float* __restrict__ Wd,
    const float* __restrict__ bd, const float* __restrict__ ah,
    float* __restrict__ scores, int wb)
{
    __shared__ __align__(16) unsigned short att_s[64][SC_LDA];
    __shared__ __align__(16) unsigned short wa_s[224][SC_LDA];
    __shared__ float ba_s[224];
    __shared__ float wd_s[224];
    __shared__ float part_s[64][2];

    int tid  = threadIdx.x;
    int wave = tid >> 6;
    int lane = tid & 63;
    int lx   = lane & 15;
    int quad = lane >> 4;
    int mg   = wave >> 1;
    int ng   = wave & 1;
    size_t row0 = (size_t)blockIdx.x * 64;

    if (tid < 224) {
        ba_s[tid] = (tid < cA) ? ba[tid] : 0.f;
        wd_s[tid] = (tid < cA) ? Wd[tid] : 0.f;
    }

    int a_r = tid >> 4, a_c = (tid & 15) * 4;
    int w_r = tid >> 3, w_c = (tid & 7) * 8;
    const float* attA = att + (row0 + a_r) * cR + a_c;
    unsigned short* wbA = att_bf + (row0 + a_r) * cR + a_c;

    f32x4 acc[2][7];
    #pragma unroll
    for (int m = 0; m < 2; ++m)
        #pragma unroll
        for (int c = 0; c < 7; ++c) acc[m][c] = (f32x4){0.f, 0.f, 0.f, 0.f};

    float4 patt[4];
    us8    pwa[7];
    #pragma unroll
    for (int i = 0; i < 4; ++i)
        patt[i] = *(const float4*)(attA + (size_t)i * 16 * cR);
    #pragma unroll
    for (int i = 0; i < 7; ++i) {
        int r = w_r + 32 * i;
        pwa[i] = (r < cA) ? *(const us8*)(wa_bf + (size_t)r * cR + w_c)
                          : (us8){0,0,0,0,0,0,0,0};
    }

    for (int k0 = 0; k0 < cR; k0 += 64) {
        #pragma unroll
        for (int i = 0; i < 4; ++i) {
            float4 v = patt[i];
            ushort4 bv;
            bv.x = f2bf(v.x); bv.y = f2bf(v.y); bv.z = f2bf(v.z); bv.w = f2bf(v.w);
            *(ushort4*)&att_s[a_r + 16 * i][a_c] = bv;
            if (wb)
                *(ushort4*)(wbA + (size_t)i * 16 * cR + k0) = bv;
        }
        #pragma unroll
        for (int i = 0; i < 7; ++i)
            *(us8*)&wa_s[w_r + 32 * i][w_c] = pwa[i];
        if (k0 + 64 < cR) {
            #pragma unroll
            for (int i = 0; i < 4; ++i)
                patt[i] = *(const float4*)(attA + (size_t)i * 16 * cR + k0 + 64);
            #pragma unroll
            for (int i = 0; i < 7; ++i) {
                int r = w_r + 32 * i;
                pwa[i] = (r < cA) ? *(const us8*)(wa_bf + (size_t)r * cR + k0 + 64 + w_c)
                                  : (us8){0,0,0,0,0,0,0,0};
            }
        }
        __syncthreads();
        #pragma unroll
        for (int ks = 0; ks < 2; ++ks) {
            int kb = ks * 32 + quad * 8;
            bf16x8 af[2];
            #pragma unroll
            for (int m = 0; m < 2; ++m)
                af[m] = *(const bf16x8*)&att_s[mg * 32 + m * 16 + lx][kb];
            #pragma unroll
            for (int c = 0; c < 7; ++c) {
                bf16x8 bfr = *(const bf16x8*)&wa_s[ng * 112 + c * 16 + lx][kb];
                #pragma unroll
                for (int m = 0; m < 2; ++m)
                    acc[m][c] = __builtin_amdgcn_mfma_f32_16x16x32_bf16(af[m], bfr, acc[m][c], 0, 0, 0);
            }
        }
        __syncthreads();
    }

    #pragma unroll
    for (int m = 0; m < 2; ++m) {
        #pragma unroll
        for (int reg = 0; reg < 4; ++reg) {
            int rl = mg * 32 + m * 16 + quad * 4 + reg;
            float ahv = ah[row0 + rl];
            float part = 0.f;
            #pragma unroll
            for (int c = 0; c < 7; ++c) {
                int col = ng * 112 + c * 16 + lx;
                part += tanhf(acc[m][c][reg] + ba_s[col] + ahv) * wd_s[col];
            }
            part += __shfl_xor(part, 1);
            part += __shfl_xor(part, 2);
            part += __shfl_xor(part, 4);
            part += __shfl_xor(part, 8);
            if (lx == 0) part_s[rl][ng] = part;
        }
    }
    __syncthreads();
    if (tid < 64)
        scores[row0 + tid] = part_s[tid][0] + part_s[tid][1] + bd[0];
}

__device__ inline void softmax_w(const float* scores, int b, int t, float* red,
                                 float* w_s)
{
    float s = (t < cA) ? scores[b * cA + t] : -INFINITY;
    red[t] = s; __syncthreads();
    for (int off = 128; off > 0; off >>= 1) {
        if (t < off) red[t] = fmaxf(red[t], red[t + off]);
        __syncthreads();
    }
    float mx = red[0];
    __syncthreads();
    float e = (t < cA) ? expf(s - mx) : 0.f;
    red[t] = e; __syncthreads();
    for (int off = 128; off > 0; off >>= 1) {
        if (t < off) red[t] += red[t + off];
        __syncthreads();
    }
    float inv = 1.f / red[0];
    if (t < cA) w_s[t] = e * inv;
    __syncthreads();
}

__global__ __launch_bounds__(256) void k_attres_f32(
    const float* __restrict__ scores, const float* __restrict__ att,
    const float* __restrict__ addin,
    float* __restrict__ out, unsigned short* __restrict__ out_bf)
{
    __shared__ float red[256];
    __shared__ float w_s[cA];
    int b = blockIdx.x, t = threadIdx.x;
    softmax_w(scores, b, t, red, w_s);

    const float* attb = att + (size_t)b * cA * cR + 2 * t;
    float acc0 = 0.f, acc1 = 0.f;
    #pragma unroll 4
    for (int a = 0; a < cA; ++a) {
        float2 u = *(const float2*)(attb + (size_t)a * cR);
        float w = w_s[a];
        acc0 += u.x * w;
        acc1 += u.y * w;
    }
    if (addin) {
        acc0 += addin[b * cR + 2 * t];
        acc1 += addin[b * cR + 2 * t + 1];
    }
    out[b * cR + 2 * t]     = acc0;
    out[b * cR + 2 * t + 1] = acc1;
    out_bf[b * cR + 2 * t]     = f2bf(acc0);
    out_bf[b * cR + 2 * t + 1] = f2bf(acc1);
}

// ---------------------------------------------------------------------------
// k_sums: sums[b,j] = bi+bh+ba + x.Wi + h.Wh + ar.Wa. Tile 32x64,
// grid (8,32), pipelined, __syncthreads.
// ---------------------------------------------------------------------------
__global__ __launch_bounds__(256, 4) void k_sums(
    const unsigned short* __restrict__ x_bf,
    const unsigned short* __restrict__ h_bf,
    const unsigned short* __restrict__ ar_bf,
    const float* __restrict__ Wi, const float* __restrict__ Wh,
    const float* __restrict__ Wa,
    const float* __restrict__ bi, const float* __restrict__ bh,
    const float* __restrict__ ba, float* __restrict__ out)
{
    __shared__ __align__(16) unsigned short a_s[32][SC_LDA];
    __shared__ __align__(16) unsigned short w_s[64][SC_LDA];
    int tid  = threadIdx.x;
    int wave = tid >> 6;
    int lane = tid & 63;
    int lx   = lane & 15;
    int quad = lane >> 4;
    int b0 = blockIdx.x * 32;
    int j0 = blockIdx.y * 64;

    const unsigned short* Aarr[3] = {x_bf, h_bf, ar_bf};
    const float* Warr[3] = {Wi, Wh, Wa};

    int a_r = tid >> 3, a_c = (tid & 7) * 8;
    int w_r = tid >> 4, w_c = (tid & 15) * 4;

    f32x4 acc0 = {0.f, 0.f, 0.f, 0.f}, acc1 = {0.f, 0.f, 0.f, 0.f};

    us8 pa;
    float4 pw[4];
    pa = *(const us8*)(Aarr[0] + (size_t)(b0 + a_r) * cR + a_c);
    #pragma unroll
    for (int i = 0; i < 4; ++i)
        pw[i] = *(const float4*)(Warr[0] + (size_t)(j0 + w_r + 16 * i) * cR + w_c);

    for (int it = 0; it < 24; ++it) {
        *(us8*)&a_s[a_r][a_c] = pa;
        #pragma unroll
        for (int i = 0; i < 4; ++i) {
            float4 v = pw[i];
            ushort4 bv;
            bv.x = f2bf(v.x); bv.y = f2bf(v.y); bv.z = f2bf(v.z); bv.w = f2bf(v.w);
            *(ushort4*)&w_s[w_r + 16 * i][w_c] = bv;
        }
        if (it < 23) {
            int s2 = (it + 1) >> 3, k2 = ((it + 1) & 7) * 64;
            pa = *(const us8*)(Aarr[s2] + (size_t)(b0 + a_r) * cR + k2 + a_c);
            #pragma unroll
            for (int i = 0; i < 4; ++i)
                pw[i] = *(const float4*)(Warr[s2] + (size_t)(j0 + w_r + 16 * i) * cR + k2 + w_c);
        }
        __syncthreads();
        #pragma unroll
        for (int ks = 0; ks < 2; ++ks) {
            int kb = ks * 32 + quad * 8;
            bf16x8 afr0 = *(const bf16x8*)&a_s[lx][kb];
            bf16x8 afr1 = *(const bf16x8*)&a_s[16 + lx][kb];
            bf16x8 bfr  = *(const bf16x8*)&w_s[wave * 16 + lx][kb];
            acc0 = __builtin_amdgcn_mfma_f32_16x16x32_bf16(afr0, bfr, acc0, 0, 0, 0);
            acc1 = __builtin_amdgcn_mfma_f32_16x16x32_bf16(afr1, bfr, acc1, 0, 0, 0);
        }
        __syncthreads();
    }
    int j = j0 + wave * 16 + lx;
    float bsum = bi[j] + bh[j] + ba[j];
    #pragma unroll
    for (int reg = 0; reg < 4; ++reg) {
        int b = b0 + quad * 4 + reg;
        out[(size_t)b * cH4 + j]        = acc0[reg] + bsum;
        out[(size_t)(b + 16) * cH4 + j] = acc1[reg] + bsum;
    }
}

// ---------------------------------------------------------------------------
// k_lin: out[b,j] = bias[j] + in.W[j]. Tile M=128 x N=64, grid (2,157).
// ---------------------------------------------------------------------------
__global__ __launch_bounds__(256, 3) void k_lin(
    const unsigned short* __restrict__ in_bf, const float* __restrict__ W,
    const float* __restrict__ bias, float* __restrict__ out, int N)
{
    __shared__ __align__(16) unsigned short a_s[128][SC_LDA];
    __shared__ __align__(16) unsigned short w_s[64][SC_LDA];
    int tid  = threadIdx.x;
    int wave = tid >> 6;
    int lane = tid & 63;
    int lx   = lane & 15;
    int quad = lane >> 4;
    int mg   = wave >> 1;
    int ng   = wave & 1;
    int b0 = blockIdx.x * 128;
    int j0 = blockIdx.y * 64;

    int a_r = tid >> 3, a_c = (tid & 7) * 8;
    int w_r = tid >> 4, w_c = (tid & 15) * 4;

    f32x4 acc[4][2];
    #pragma unroll
    for (int m = 0; m < 4; ++m)
        #pragma unroll
        for (int c = 0; c < 2; ++c) acc[m][c] = (f32x4){0.f, 0.f, 0.f, 0.f};

    us8 pa[4];
    float4 pw[4];
    #pragma unroll
    for (int i = 0; i < 4; ++i)
        pa[i] = *(const us8*)(in_bf + (size_t)(b0 + a_r + 32 * i) * cR + a_c);
    #pragma unroll
    for (int i = 0; i < 4; ++i) {
        int r = j0 + w_r + 16 * i;
        pw[i] = (r < N) ? *(const float4*)(W + (size_t)r * cR + w_c)
                        : make_float4(0.f, 0.f, 0.f, 0.f);
    }

    for (int k0 = 0; k0 < cR; k0 += 64) {
        #pragma unroll
        for (int i = 0; i < 4; ++i)
            *(us8*)&a_s[a_r + 32 * i][a_c] = pa[i];
        #pragma unroll
        for (int i = 0; i < 4; ++i) {
            float4 v = pw[i];
            ushort4 bv;
            bv.x = f2bf(v.x); bv.y = f2bf(v.y); bv.z = f2bf(v.z); bv.w = f2bf(v.w);
            *(ushort4*)&w_s[w_r + 16 * i][w_c] = bv;
        }
        if (k0 + 64 < cR) {
            #pragma unroll
            for (int i = 0; i < 4; ++i)
                pa[i] = *(const us8*)(in_bf + (size_t)(b0 + a_r + 32 * i) * cR + k0 + 64 + a_c);
            #pragma unroll
            for (int i = 0; i < 4; ++i) {
                int r = j0 + w_r + 16 * i;
                pw[i] = (r < N) ? *(const float4*)(W + (size_t)r * cR + k0 + 64 + w_c)
                                : make_float4(0.f, 0.f, 0.f, 0.f);
            }
        }
        __syncthreads();
        #pragma unroll
        for (int ks = 0; ks < 2; ++ks) {
            int kb = ks * 32 + quad * 8;
            bf16x8 af[4];
            #pragma unroll
            for (int m = 0; m < 4; ++m)
                af[m] = *(const bf16x8*)&a_s[mg * 64 + m * 16 + lx][kb];
            #pragma unroll
            for (int c = 0; c < 2; ++c) {
                bf16x8 bfr = *(const bf16x8*)&w_s[ng * 32 + c * 16 + lx][kb];
                #pragma unroll
                for (int m = 0; m < 4; ++m)
                    acc[m][c] = __builtin_amdgcn_mfma_f32_16x16x32_bf16(af[m], bfr, acc[m][c], 0, 0, 0);
            }
        }
        __syncthreads();
    }
    #pragma unroll
    for (int c = 0; c < 2; ++c) {
        int j = j0 + ng * 32 + c * 16 + lx;
        if (j < N) {
            float bv = bias[j];
            #pragma unroll
            for (int m = 0; m < 4; ++m) {
                #pragma unroll
                for (int reg = 0; reg < 4; ++reg) {
                    int b = b0 + mg * 64 + m * 16 + quad * 4 + reg;
                    out[(size_t)b * N + j] = acc[m][c][reg] + bv;
                }
            }
        }
    }
}

// ---------------------------------------------------------------------------
__global__ __launch_bounds__(256) void k_cell(
    const float* __restrict__ sums, const float* __restrict__ prev_c,
    float* __restrict__ next_c, float* __restrict__ next_h)
{
    int idx = blockIdx.x * 256 + threadIdx.x;
    int b = idx >> 9;
    int j = idx & 511;
    const float* srow = sums + (size_t)b * cH4;
    float ig = 1.f / (1.f + expf(-srow[j]));
    float fg = 1.f / (1.f + expf(-srow[cR + j]));
    float og = 1.f / (1.f + expf(-srow[2 * cR + j]));
    float gt = tanhf(srow[3 * cR + j]);
    float c = fg * prev_c[idx] + ig * gt;
    float hh = og * tanhf(c);
    next_c[idx] = c;
    next_h[idx] = hh;
}

__global__ __launch_bounds__(256) void k_logsoftmax(float* __restrict__ logits)
{
    __shared__ float red[256];
    int b = blockIdx.x, t = threadIdx.x;
    float* row = logits + (size_t)b * cV;
    const float4* row4 = (const float4*)row;
    float mx = -INFINITY;
    for (int v = t; v < cV / 4; v += 256) {
        float4 f = row4[v];
        mx = fmaxf(mx, fmaxf(fmaxf(f.x, f.y), fmaxf(f.z, f.w)));
    }
    red[t] = mx; __syncthreads();
    for (int off = 128; off > 0; off >>= 1) {
        if (t < off) red[t] = fmaxf(red[t], red[t + off]);
        __syncthreads();
    }
    mx = red[0]; __syncthreads();
    float sum = 0.f;
    for (int v = t; v < cV / 4; v += 256) {
        float4 f = row4[v];
        sum += expf(f.x - mx) + expf(f.y - mx) + expf(f.z - mx) + expf(f.w - mx);
    }
    red[t] = sum; __syncthreads();
    for (int off = 128; off > 0; off >>= 1) {
        if (t < off) red[t] += red[t + off];
        __syncthreads();
    }
    float lse = mx + logf(red[0]);
    for (int v = t; v < cV / 4; v += 256) {
        float4 f = row4[v];
        f.x -= lse; f.y -= lse; f.z -= lse; f.w -= lse;
        ((float4*)row)[v] = f;
    }
}

// ---------------------------------------------------------------------------
extern "C" void kernel_launch(void* const* d_in, const int* in_sizes, int n_in,
                              void* d_out, int out_size, void* d_ws, size_t ws_size,
                              hipStream_t stream)
{
    const float* x      = (const float*)d_in[0];
    const float* att    = (const float*)d_in[1];
    const float* prev_c = (const float*)d_in[2];
    const float* prev_h = (const float*)d_in[3];
    const float* W_a2a  = (const float*)d_in[4];
    const float* b_a2a  = (const float*)d_in[5];
    const float* W_h2a  = (const float*)d_in[6];
    const float* b_h2a  = (const float*)d_in[7];
    const float* W_d2d  = (const float*)d_in[8];
    const float* b_d2d  = (const float*)d_in[9];
    const float* W_i2h  = (const float*)d_in[10];
    const float* b_i2h  = (const float*)d_in[11];
    const float* W_a2h  = (const float*)d_in[12];
    const float* b_a2h  = (const float*)d_in[13];
    const float* W_h2h  = (const float*)d_in[14];
    const float* b_h2h  = (const float*)d_in[15];
    const float* W_a2a1 = (const float*)d_in[16];
    const float* b_a2a1 = (const float*)d_in[17];
    const float* W_h2a1 = (const float*)d_in[18];
    const float* b_h2a1 = (const float*)d_in[19];
    const float* W_d2d1 = (const float*)d_in[20];
    const float* b_d2d1 = (const float*)d_in[21];
    const float* W_proj = (const float*)d_in[22];
    const float* b_proj = (const float*)d_in[23];

    float* out_next_c = (float*)d_out;                   // B*R
    float* out_top_h  = out_next_c + (size_t)cB * cR;    // B*R
    float* out_logits = out_top_h  + (size_t)cB * cR;    // B*V

    const size_t ATT_FLOATS = 12845056;   // 25,690,112 bf16
    const size_t NEED_A = (ATT_FLOATS + 1445888) * sizeof(float);
    bool bigws = ws_size >= NEED_A;

    float* ws = (float*)d_ws;
    unsigned short* att_bf = (unsigned short*)ws;         // path A only
    float* p = bigws ? (ws + ATT_FLOATS) : ws;
    unsigned short* wa2a_bf  = (unsigned short*)p;  p += 50176;
    unsigned short* wa2a1_bf = (unsigned short*)p;  p += 50176;
    unsigned short* x_bf     = (unsigned short*)p;  p += 65536;
    unsigned short* h_bf     = (unsigned short*)p;  p += 65536;
    unsigned short* ar1_bf   = (unsigned short*)p;  p += 65536;
    unsigned short* ar2_bf   = (unsigned short*)p;  p += 65536;
    unsigned short* toph_bf  = (unsigned short*)p;  p += 65536;
    float* ws_ah      = p;  p += 50176;
    float* ws_scores  = p;  p += 50176;
    float* ws_attres1 = p;  p += 131072;
    float* ws_attres2 = p;  p += 131072;
    float* ws_sums    = p;  p += 524288;
    float* ws_next_h  = p;  p += 131072;

    // fused-attend partial buffers (reuse: pnum lives in ws_sums, consumed
    // before k_sums writes / after k_cell reads; pm/pden live in ws_scores)
    float* pnum = ws_sums;            // 1024 * 512 floats = exactly ws_sums
    float* pm   = ws_scores;          // 1024
    float* pden = ws_scores + 1024;   // 1024

    // ---- small bf16 conversions (one launch) ----
    k_cvt4<<<452, 256, 0, stream>>>(W_a2a, wa2a_bf, 98,
                                    W_a2a1, wa2a1_bf, 98,
                                    x, x_bf, 128,
                                    prev_h, h_bf, 128);

    // ---- attend 1 (prev_h) ----
    k_ah<<<cB, 256, 0, stream>>>(prev_h, W_h2a, b_h2a, ws_ah);
    if (bigws) {
        k_attf1<<<cB * 4, 256, 0, stream>>>(att, att_bf, wa2a_bf,
                                            b_a2a, W_d2d, b_d2d, ws_ah,
                                            pnum, pm, pden);
        k_attfin<<<cB, 256, 0, stream>>>(pnum, pm, pden, nullptr,
                                         ws_attres1, ar1_bf);
    } else {
        k_scores_cv<<<(cB * cA) / 64, 256, 0, stream>>>(att, att_bf, wa2a_bf,
                                                        b_a2a, W_d2d, b_d2d,
                                                        ws_ah, ws_scores, 0);
        k_attres_f32<<<cB, 256, 0, stream>>>(ws_scores, att, nullptr,
                                             ws_attres1, ar1_bf);
    }

    // ---- gates + LSTM cell ----
    k_sums<<<dim3(8, 32), 256, 0, stream>>>(x_bf, h_bf, ar1_bf,
                                            W_i2h, W_h2h, W_a2h,
                                            b_i2h, b_h2h, b_a2h, ws_sums);
    k_cell<<<(cB * cR) / 256, 256, 0, stream>>>(ws_sums, prev_c, out_next_c, ws_next_h);

    // ---- attend 2 (next_h); fused top_h = attres2 + next_h ----
    k_ah<<<cB, 256, 0, stream>>>(ws_next_h, W_h2a1, b_h2a1, ws_ah);
    if (bigws) {
        k_attf2<<<cB * 4, 256, 0, stream>>>(att_bf, wa2a1_bf,
                                            b_a2a1, W_d2d1, b_d2d1, ws_ah,
                                            pnum, pm, pden);
        k_attfin<<<cB, 256, 0, stream>>>(pnum, pm, pden, ws_next_h,
                                         out_top_h, toph_bf);
    } else {
        k_scores_cv<<<(cB * cA) / 64, 256, 0, stream>>>(att, att_bf, wa2a1_bf,
                                                        b_a2a1, W_d2d1, b_d2d1,
                                                        ws_ah, ws_scores, 0);
        k_attres_f32<<<cB, 256, 0, stream>>>(ws_scores, att, ws_next_h,
                                             out_top_h, toph_bf);
    }

    // ---- projection + log_softmax ----
    k_lin<<<dim3(2, 157), 256, 0, stream>>>(toph_bf, W_proj, b_proj, out_logits, cV);
    k_logsoftmax<<<cB, 256, 0, stream>>>(out_logits);
}

// Round 4
// 362.423 us; speedup vs baseline: 1.3935x; 1.3935x over previous
//
#include <hip/hip_runtime.h>
#include <math.h>

constexpr int cB  = 256;
constexpr int cI  = 512;
constexpr int cR  = 512;
constexpr int cA  = 196;
constexpr int cV  = 10000;
constexpr int cH4 = 2048;   // 4*R

typedef short bf16x8 __attribute__((ext_vector_type(8)));
typedef float f32x4  __attribute__((ext_vector_type(4)));
typedef unsigned short us8 __attribute__((ext_vector_type(8)));

__device__ inline unsigned short f2bf(float f) {
    unsigned int u = __float_as_uint(f);
    u += 0x7fffu + ((u >> 16) & 1u);
    return (unsigned short)(u >> 16);
}
__device__ inline float bf2f(unsigned short s) {
    return __uint_as_float(((unsigned int)s) << 16);
}
// fast tanh: 1 - 2/(1+e^{2x}); exact at +-inf, ~1e-7 rel err, v_exp-based
__device__ inline float tanh_f(float x) {
    return 1.f - 2.f / (1.f + __expf(2.f * x));
}

// ---------------------------------------------------------------------------
// k_cvt_ah: four fp32->bf16 conversions (452 blocks) + attend-1 "ah" GEMV
// (256 blocks) in ONE launch. The two are independent; merging saves a
// launch + tail. Blocks < ncvt do conversion; the rest do ah.
// ---------------------------------------------------------------------------
__global__ __launch_bounds__(256) void k_cvt_ah(
    const float* __restrict__ s0, unsigned short* __restrict__ d0, int nb0,
    const float* __restrict__ s1, unsigned short* __restrict__ d1, int nb1,
    const float* __restrict__ s2, unsigned short* __restrict__ d2, int nb2,
    const float* __restrict__ s3, unsigned short* __restrict__ d3, int nb3,
    const float* __restrict__ h, const float* __restrict__ W,
    const float* __restrict__ bias, float* __restrict__ outah)
{
    __shared__ __align__(16) float h_s[cR];
    int blk = blockIdx.x;
    int ncvt = nb0 + nb1 + nb2 + nb3;
    int t = threadIdx.x;
    if (blk < ncvt) {
        const float* src; unsigned short* dst; int base;
        if (blk < nb0)                  { src = s0; dst = d0; base = blk; }
        else if (blk < nb0 + nb1)       { src = s1; dst = d1; base = blk - nb0; }
        else if (blk < nb0 + nb1 + nb2) { src = s2; dst = d2; base = blk - nb0 - nb1; }
        else                            { src = s3; dst = d3; base = blk - nb0 - nb1 - nb2; }
        int i = base * 256 + t;
        float4 v = ((const float4*)src)[i];
        ushort4 b;
        b.x = f2bf(v.x); b.y = f2bf(v.y); b.z = f2bf(v.z); b.w = f2bf(v.w);
        ((ushort4*)dst)[i] = b;
    } else {
        int b = blk - ncvt;
        h_s[t]       = h[b * cR + t];
        h_s[t + 256] = h[b * cR + t + 256];
        __syncthreads();
        if (t < cA) {
            const float4* Wv = (const float4*)(W + (size_t)t * cR);
            const float4* hv = (const float4*)h_s;
            float acc = 0.f;
            #pragma unroll 4
            for (int k = 0; k < cR / 4; ++k) {
                float4 w4 = Wv[k], x4 = hv[k];
                acc += w4.x * x4.x + w4.y * x4.y + w4.z * x4.z + w4.w * x4.w;
            }
            outah[b * cA + t] = acc + bias[t];
        }
    }
}

// ---------------------------------------------------------------------------
// k_ah: out[b,o] = bias[o] + sum_k h[b,k] * W[o,k]   (o < cA)  fp32
// ---------------------------------------------------------------------------
__global__ __launch_bounds__(256) void k_ah(
    const float* __restrict__ h, const float* __restrict__ W,
    const float* __restrict__ bias, float* __restrict__ out)
{
    __shared__ __align__(16) float h_s[cR];
    int b = blockIdx.x;
    int t = threadIdx.x;
    h_s[t]       = h[b * cR + t];
    h_s[t + 256] = h[b * cR + t + 256];
    __syncthreads();
    if (t < cA) {
        const float4* Wv = (const float4*)(W + (size_t)t * cR);
        const float4* hv = (const float4*)h_s;
        float acc = 0.f;
        #pragma unroll 4
        for (int k = 0; k < cR / 4; ++k) {
            float4 w4 = Wv[k], x4 = hv[k];
            acc += w4.x * x4.x + w4.y * x4.y + w4.z * x4.z + w4.w * x4.w;
        }
        out[b * cA + t] = acc + bias[t];
    }
}

// ---------------------------------------------------------------------------
// k_scores_cv: fused GEMM (B*A x 196 x 512) + tanh/dot epilogue.
// ROUND-4: reverted to the round-0 M=128 structure (best measured: 70.7us;
// M=64/M=32/49-row-fusion restructures all regressed). Only change vs R0:
// fast tanh_f in the epilogue (112 libm tanhf/thread -> v_exp based).
// ---------------------------------------------------------------------------
constexpr int SC_LDA = 72;   // bf16 elems per LDS row (144 B, 2-way alias free)

__global__ __launch_bounds__(256, 2) void k_scores_cv(
    const float* __restrict__ att, unsigned short* __restrict__ att_bf,
    const unsigned short* __restrict__ wa_bf,
    const float* __restrict__ ba, const float* __restrict__ Wd,
    const float* __restrict__ bd, const float* __restrict__ ah,
    float* __restrict__ scores, int wb)
{
    __shared__ __align__(16) unsigned short att_s[128][SC_LDA];
    __shared__ __align__(16) unsigned short wa_s[224][SC_LDA];
    __shared__ float ba_s[224];
    __shared__ float wd_s[224];
    __shared__ float part_s[128][2];

    int tid  = threadIdx.x;
    int wave = tid >> 6;
    int lane = tid & 63;
    int lx   = lane & 15;
    int quad = lane >> 4;
    int mg   = wave >> 1;          // row group: rows mg*64 .. +63
    int ng   = wave & 1;           // col group: cols ng*112 .. +111
    size_t row0 = (size_t)blockIdx.x * 128;

    if (tid < 224) {
        ba_s[tid] = (tid < cA) ? ba[tid] : 0.f;
        wd_s[tid] = (tid < cA) ? Wd[tid] : 0.f;
    }

    int a_r = tid >> 4, a_c = (tid & 15) * 4;   // att: rows a_r+16i, i<8
    int w_r = tid >> 3, w_c = (tid & 7) * 8;    // wa : rows w_r+32i, i<7 (224*8=1792=7*256)
    const float* attA = att + (row0 + a_r) * cR + a_c;
    unsigned short* wbA = att_bf + (row0 + a_r) * cR + a_c;

    f32x4 acc[4][7];
    #pragma unroll
    for (int m = 0; m < 4; ++m)
        #pragma unroll
        for (int c = 0; c < 7; ++c) acc[m][c] = (f32x4){0.f, 0.f, 0.f, 0.f};

    float4 patt[8];
    us8    pwa[7];
    #pragma unroll
    for (int i = 0; i < 8; ++i)
        patt[i] = *(const float4*)(attA + (size_t)i * 16 * cR);
    #pragma unroll
    for (int i = 0; i < 7; ++i) {
        int r = w_r + 32 * i;
        pwa[i] = (r < cA) ? *(const us8*)(wa_bf + (size_t)r * cR + w_c)
                          : (us8){0,0,0,0,0,0,0,0};
    }

    for (int k0 = 0; k0 < cR; k0 += 64) {
        #pragma unroll
        for (int i = 0; i < 8; ++i) {
            float4 v = patt[i];
            ushort4 bv;
            bv.x = f2bf(v.x); bv.y = f2bf(v.y); bv.z = f2bf(v.z); bv.w = f2bf(v.w);
            *(ushort4*)&att_s[a_r + 16 * i][a_c] = bv;
            if (wb)
                *(ushort4*)(wbA + (size_t)i * 16 * cR + k0) = bv;
        }
        #pragma unroll
        for (int i = 0; i < 7; ++i)
            *(us8*)&wa_s[w_r + 32 * i][w_c] = pwa[i];
        if (k0 + 64 < cR) {
            #pragma unroll
            for (int i = 0; i < 8; ++i)
                patt[i] = *(const float4*)(attA + (size_t)i * 16 * cR + k0 + 64);
            #pragma unroll
            for (int i = 0; i < 7; ++i) {
                int r = w_r + 32 * i;
                pwa[i] = (r < cA) ? *(const us8*)(wa_bf + (size_t)r * cR + k0 + 64 + w_c)
                                  : (us8){0,0,0,0,0,0,0,0};
            }
        }
        __syncthreads();
        #pragma unroll
        for (int ks = 0; ks < 2; ++ks) {
            int kb = ks * 32 + quad * 8;
            bf16x8 af[4];
            #pragma unroll
            for (int m = 0; m < 4; ++m)
                af[m] = *(const bf16x8*)&att_s[mg * 64 + m * 16 + lx][kb];
            #pragma unroll
            for (int c = 0; c < 7; ++c) {
                bf16x8 bfr = *(const bf16x8*)&wa_s[ng * 112 + c * 16 + lx][kb];
                #pragma unroll
                for (int m = 0; m < 4; ++m)
                    acc[m][c] = __builtin_amdgcn_mfma_f32_16x16x32_bf16(af[m], bfr, acc[m][c], 0, 0, 0);
            }
        }
        __syncthreads();
    }

    // epilogue: D mapping col=lane&15, row=quad*4+reg; cross-wave (ng) reduce
    #pragma unroll
    for (int m = 0; m < 4; ++m) {
        #pragma unroll
        for (int reg = 0; reg < 4; ++reg) {
            int rl = mg * 64 + m * 16 + quad * 4 + reg;
            float ahv = ah[row0 + rl];
            float part = 0.f;
            #pragma unroll
            for (int c = 0; c < 7; ++c) {
                int col = ng * 112 + c * 16 + lx;
                part += tanh_f(acc[m][c][reg] + ba_s[col] + ahv) * wd_s[col];
            }
            part += __shfl_xor(part, 1);
            part += __shfl_xor(part, 2);
            part += __shfl_xor(part, 4);
            part += __shfl_xor(part, 8);
            if (lx == 0) part_s[rl][ng] = part;
        }
    }
    __syncthreads();
    if (tid < 128)
        scores[row0 + tid] = part_s[tid][0] + part_s[tid][1] + bd[0];
}

// ---------------------------------------------------------------------------
// k_scores_bf: same structure, att already bf16.
// ---------------------------------------------------------------------------
__global__ __launch_bounds__(256, 2) void k_scores_bf(
    const unsigned short* __restrict__ att_bf,
    const unsigned short* __restrict__ wa_bf,
    const float* __restrict__ ba, const float* __restrict__ Wd,
    const float* __restrict__ bd, const float* __restrict__ ah,
    float* __restrict__ scores)
{
    __shared__ __align__(16) unsigned short att_s[128][SC_LDA];
    __shared__ __align__(16) unsigned short wa_s[224][SC_LDA];
    __shared__ float ba_s[224];
    __shared__ float wd_s[224];
    __shared__ float part_s[128][2];

    int tid  = threadIdx.x;
    int wave = tid >> 6;
    int lane = tid & 63;
    int lx   = lane & 15;
    int quad = lane >> 4;
    int mg   = wave >> 1;
    int ng   = wave & 1;
    size_t row0 = (size_t)blockIdx.x * 128;

    if (tid < 224) {
        ba_s[tid] = (tid < cA) ? ba[tid] : 0.f;
        wd_s[tid] = (tid < cA) ? Wd[tid] : 0.f;
    }

    int a_r = tid >> 3, a_c = (tid & 7) * 8;    // att: rows a_r+32i, i<4
    int w_r = tid >> 3, w_c = (tid & 7) * 8;    // wa : rows w_r+32i, i<7
    const unsigned short* attA = att_bf + (row0 + a_r) * cR + a_c;

    f32x4 acc[4][7];
    #pragma unroll
    for (int m = 0; m < 4; ++m)
        #pragma unroll
        for (int c = 0; c < 7; ++c) acc[m][c] = (f32x4){0.f, 0.f, 0.f, 0.f};

    us8 patt[4];
    us8 pwa[7];
    #pragma unroll
    for (int i = 0; i < 4; ++i)
        patt[i] = *(const us8*)(attA + (size_t)i * 32 * cR);
    #pragma unroll
    for (int i = 0; i < 7; ++i) {
        int r = w_r + 32 * i;
        pwa[i] = (r < cA) ? *(const us8*)(wa_bf + (size_t)r * cR + w_c)
                          : (us8){0,0,0,0,0,0,0,0};
    }

    for (int k0 = 0; k0 < cR; k0 += 64) {
        #pragma unroll
        for (int i = 0; i < 4; ++i)
            *(us8*)&att_s[a_r + 32 * i][a_c] = patt[i];
        #pragma unroll
        for (int i = 0; i < 7; ++i)
            *(us8*)&wa_s[w_r + 32 * i][w_c] = pwa[i];
        if (k0 + 64 < cR) {
            #pragma unroll
            for (int i = 0; i < 4; ++i)
                patt[i] = *(const us8*)(attA + (size_t)i * 32 * cR + k0 + 64);
            #pragma unroll
            for (int i = 0; i < 7; ++i) {
                int r = w_r + 32 * i;
                pwa[i] = (r < cA) ? *(const us8*)(wa_bf + (size_t)r * cR + k0 + 64 + w_c)
                                  : (us8){0,0,0,0,0,0,0,0};
            }
        }
        __syncthreads();
        #pragma unroll
        for (int ks = 0; ks < 2; ++ks) {
            int kb = ks * 32 + quad * 8;
            bf16x8 af[4];
            #pragma unroll
            for (int m = 0; m < 4; ++m)
                af[m] = *(const bf16x8*)&att_s[mg * 64 + m * 16 + lx][kb];
            #pragma unroll
            for (int c = 0; c < 7; ++c) {
                bf16x8 bfr = *(const bf16x8*)&wa_s[ng * 112 + c * 16 + lx][kb];
                #pragma unroll
                for (int m = 0; m < 4; ++m)
                    acc[m][c] = __builtin_amdgcn_mfma_f32_16x16x32_bf16(af[m], bfr, acc[m][c], 0, 0, 0);
            }
        }
        __syncthreads();
    }

    #pragma unroll
    for (int m = 0; m < 4; ++m) {
        #pragma unroll
        for (int reg = 0; reg < 4; ++reg) {
            int rl = mg * 64 + m * 16 + quad * 4 + reg;
            float ahv = ah[row0 + rl];
            float part = 0.f;
            #pragma unroll
            for (int c = 0; c < 7; ++c) {
                int col = ng * 112 + c * 16 + lx;
                part += tanh_f(acc[m][c][reg] + ba_s[col] + ahv) * wd_s[col];
            }
            part += __shfl_xor(part, 1);
            part += __shfl_xor(part, 2);
            part += __shfl_xor(part, 4);
            part += __shfl_xor(part, 8);
            if (lx == 0) part_s[rl][ng] = part;
        }
    }
    __syncthreads();
    if (tid < 128)
        scores[row0 + tid] = part_s[tid][0] + part_s[tid][1] + bd[0];
}

// ---------------------------------------------------------------------------
// softmax helper (256-thread LDS reduce over A scores)
// ---------------------------------------------------------------------------
__device__ inline void softmax_w(const float* scores, int b, int t, float* red,
                                 float* w_s)
{
    float s = (t < cA) ? scores[b * cA + t] : -INFINITY;
    red[t] = s; __syncthreads();
    for (int off = 128; off > 0; off >>= 1) {
        if (t < off) red[t] = fmaxf(red[t], red[t + off]);
        __syncthreads();
    }
    float mx = red[0];
    __syncthreads();
    float e = (t < cA) ? __expf(s - mx) : 0.f;
    red[t] = e; __syncthreads();
    for (int off = 128; off > 0; off >>= 1) {
        if (t < off) red[t] += red[t + off];
        __syncthreads();
    }
    float inv = 1.f / red[0];
    if (t < cA) w_s[t] = e * inv;
    __syncthreads();
}

// ---------------------------------------------------------------------------
// k_attres_bf: softmax + weighted sum (+ optional addin). Round-0 256-thread
// version (the 512-thread variant coincided with the +8us round-1 total).
// ---------------------------------------------------------------------------
__global__ __launch_bounds__(256) void k_attres_bf(
    const float* __restrict__ scores, const unsigned short* __restrict__ att_bf,
    const float* __restrict__ addin,
    float* __restrict__ out, unsigned short* __restrict__ out_bf)
{
    __shared__ float red[256];
    __shared__ float w_s[cA];
    __shared__ float red2[4][512];
    int b = blockIdx.x, t = threadIdx.x;
    softmax_w(scores, b, t, red, w_s);

    int p = t >> 6, l = t & 63;
    const unsigned short* base = att_bf + (size_t)b * cA * cR + l * 8;
    float acc[8] = {};
    #pragma unroll 7
    for (int a = p; a < cA; a += 4) {
        us8 v = *(const us8*)(base + (size_t)a * cR);
        float w = w_s[a];
        #pragma unroll
        for (int j = 0; j < 8; ++j)
            acc[j] += bf2f(v[j]) * w;
    }
    #pragma unroll
    for (int j = 0; j < 8; ++j)
        red2[p][l * 8 + j] = acc[j];
    __syncthreads();
    #pragma unroll
    for (int rr = 0; rr < 2; ++rr) {
        int r = t + rr * 256;
        float s = red2[0][r] + red2[1][r] + red2[2][r] + red2[3][r];
        if (addin) s += addin[b * cR + r];
        out[b * cR + r] = s;
        out_bf[b * cR + r] = f2bf(s);
    }
}

// fallback (small ws): fp32 att
__global__ __launch_bounds__(256) void k_attres_f32(
    const float* __restrict__ scores, const float* __restrict__ att,
    const float* __restrict__ addin,
    float* __restrict__ out, unsigned short* __restrict__ out_bf)
{
    __shared__ float red[256];
    __shared__ float w_s[cA];
    int b = blockIdx.x, t = threadIdx.x;
    softmax_w(scores, b, t, red, w_s);

    const float* attb = att + (size_t)b * cA * cR + 2 * t;
    float acc0 = 0.f, acc1 = 0.f;
    #pragma unroll 4
    for (int a = 0; a < cA; ++a) {
        float2 u = *(const float2*)(attb + (size_t)a * cR);
        float w = w_s[a];
        acc0 += u.x * w;
        acc1 += u.y * w;
    }
    if (addin) {
        acc0 += addin[b * cR + 2 * t];
        acc1 += addin[b * cR + 2 * t + 1];
    }
    out[b * cR + 2 * t]     = acc0;
    out[b * cR + 2 * t + 1] = acc1;
    out_bf[b * cR + 2 * t]     = f2bf(acc0);
    out_bf[b * cR + 2 * t + 1] = f2bf(acc1);
}

// ---------------------------------------------------------------------------
// k_sums: sums[b,j] = bi+bh+ba + x.Wi + h.Wh + ar.Wa. Tile 32x64,
// grid (8,32), pipelined, __syncthreads.
// ---------------------------------------------------------------------------
__global__ __launch_bounds__(256, 4) void k_sums(
    const unsigned short* __restrict__ x_bf,
    const unsigned short* __restrict__ h_bf,
    const unsigned short* __restrict__ ar_bf,
    const float* __restrict__ Wi, const float* __restrict__ Wh,
    const float* __restrict__ Wa,
    const float* __restrict__ bi, const float* __restrict__ bh,
    const float* __restrict__ ba, float* __restrict__ out)
{
    __shared__ __align__(16) unsigned short a_s[32][SC_LDA];
    __shared__ __align__(16) unsigned short w_s[64][SC_LDA];
    int tid  = threadIdx.x;
    int wave = tid >> 6;
    int lane = tid & 63;
    int lx   = lane & 15;
    int quad = lane >> 4;
    int b0 = blockIdx.x * 32;
    int j0 = blockIdx.y * 64;

    const unsigned short* Aarr[3] = {x_bf, h_bf, ar_bf};
    const float* Warr[3] = {Wi, Wh, Wa};

    int a_r = tid >> 3, a_c = (tid & 7) * 8;
    int w_r = tid >> 4, w_c = (tid & 15) * 4;

    f32x4 acc0 = {0.f, 0.f, 0.f, 0.f}, acc1 = {0.f, 0.f, 0.f, 0.f};

    us8 pa;
    float4 pw[4];
    pa = *(const us8*)(Aarr[0] + (size_t)(b0 + a_r) * cR + a_c);
    #pragma unroll
    for (int i = 0; i < 4; ++i)
        pw[i] = *(const float4*)(Warr[0] + (size_t)(j0 + w_r + 16 * i) * cR + w_c);

    for (int it = 0; it < 24; ++it) {
        *(us8*)&a_s[a_r][a_c] = pa;
        #pragma unroll
        for (int i = 0; i < 4; ++i) {
            float4 v = pw[i];
            ushort4 bv;
            bv.x = f2bf(v.x); bv.y = f2bf(v.y); bv.z = f2bf(v.z); bv.w = f2bf(v.w);
            *(ushort4*)&w_s[w_r + 16 * i][w_c] = bv;
        }
        if (it < 23) {
            int s2 = (it + 1) >> 3, k2 = ((it + 1) & 7) * 64;
            pa = *(const us8*)(Aarr[s2] + (size_t)(b0 + a_r) * cR + k2 + a_c);
            #pragma unroll
            for (int i = 0; i < 4; ++i)
                pw[i] = *(const float4*)(Warr[s2] + (size_t)(j0 + w_r + 16 * i) * cR + k2 + w_c);
        }
        __syncthreads();
        #pragma unroll
        for (int ks = 0; ks < 2; ++ks) {
            int kb = ks * 32 + quad * 8;
            bf16x8 afr0 = *(const bf16x8*)&a_s[lx][kb];
            bf16x8 afr1 = *(const bf16x8*)&a_s[16 + lx][kb];
            bf16x8 bfr  = *(const bf16x8*)&w_s[wave * 16 + lx][kb];
            acc0 = __builtin_amdgcn_mfma_f32_16x16x32_bf16(afr0, bfr, acc0, 0, 0, 0);
            acc1 = __builtin_amdgcn_mfma_f32_16x16x32_bf16(afr1, bfr, acc1, 0, 0, 0);
        }
        __syncthreads();
    }
    int j = j0 + wave * 16 + lx;
    float bsum = bi[j] + bh[j] + ba[j];
    #pragma unroll
    for (int reg = 0; reg < 4; ++reg) {
        int b = b0 + quad * 4 + reg;
        out[(size_t)b * cH4 + j]        = acc0[reg] + bsum;
        out[(size_t)(b + 16) * cH4 + j] = acc1[reg] + bsum;
    }
}

// ---------------------------------------------------------------------------
// k_lin: out[b,j] = bias[j] + in.W[j]. Tile M=128 x N=64, grid (2,157):
// W_proj read 2x. 2x2 wave tiling (wave = 64 rows x 32 cols), register
// prefetch.
// ---------------------------------------------------------------------------
__global__ __launch_bounds__(256, 3) void k_lin(
    const unsigned short* __restrict__ in_bf, const float* __restrict__ W,
    const float* __restrict__ bias, float* __restrict__ out, int N)
{
    __shared__ __align__(16) unsigned short a_s[128][SC_LDA];
    __shared__ __align__(16) unsigned short w_s[64][SC_LDA];
    int tid  = threadIdx.x;
    int wave = tid >> 6;
    int lane = tid & 63;
    int lx   = lane & 15;
    int quad = lane >> 4;
    int mg   = wave >> 1;          // rows mg*64 + m*16, m<4
    int ng   = wave & 1;           // cols ng*32 + c*16, c<2
    int b0 = blockIdx.x * 128;
    int j0 = blockIdx.y * 64;

    int a_r = tid >> 3, a_c = (tid & 7) * 8;    // A: rows a_r+32i, i<4
    int w_r = tid >> 4, w_c = (tid & 15) * 4;   // W: rows w_r+16i, i<4

    f32x4 acc[4][2];
    #pragma unroll
    for (int m = 0; m < 4; ++m)
        #pragma unroll
        for (int c = 0; c < 2; ++c) acc[m][c] = (f32x4){0.f, 0.f, 0.f, 0.f};

    us8 pa[4];
    float4 pw[4];
    #pragma unroll
    for (int i = 0; i < 4; ++i)
        pa[i] = *(const us8*)(in_bf + (size_t)(b0 + a_r + 32 * i) * cR + a_c);
    #pragma unroll
    for (int i = 0; i < 4; ++i) {
        int r = j0 + w_r + 16 * i;
        pw[i] = (r < N) ? *(const float4*)(W + (size_t)r * cR + w_c)
                        : make_float4(0.f, 0.f, 0.f, 0.f);
    }

    for (int k0 = 0; k0 < cR; k0 += 64) {
        #pragma unroll
        for (int i = 0; i < 4; ++i)
            *(us8*)&a_s[a_r + 32 * i][a_c] = pa[i];
        #pragma unroll
        for (int i = 0; i < 4; ++i) {
            float4 v = pw[i];
            ushort4 bv;
            bv.x = f2bf(v.x); bv.y = f2bf(v.y); bv.z = f2bf(v.z); bv.w = f2bf(v.w);
            *(ushort4*)&w_s[w_r + 16 * i][w_c] = bv;
        }
        if (k0 + 64 < cR) {
            #pragma unroll
            for (int i = 0; i < 4; ++i)
                pa[i] = *(const us8*)(in_bf + (size_t)(b0 + a_r + 32 * i) * cR + k0 + 64 + a_c);
            #pragma unroll
            for (int i = 0; i < 4; ++i) {
                int r = j0 + w_r + 16 * i;
                pw[i] = (r < N) ? *(const float4*)(W + (size_t)r * cR + k0 + 64 + w_c)
                                : make_float4(0.f, 0.f, 0.f, 0.f);
            }
        }
        __syncthreads();
        #pragma unroll
        for (int ks = 0; ks < 2; ++ks) {
            int kb = ks * 32 + quad * 8;
            bf16x8 af[4];
            #pragma unroll
            for (int m = 0; m < 4; ++m)
                af[m] = *(const bf16x8*)&a_s[mg * 64 + m * 16 + lx][kb];
            #pragma unroll
            for (int c = 0; c < 2; ++c) {
                bf16x8 bfr = *(const bf16x8*)&w_s[ng * 32 + c * 16 + lx][kb];
                #pragma unroll
                for (int m = 0; m < 4; ++m)
                    acc[m][c] = __builtin_amdgcn_mfma_f32_16x16x32_bf16(af[m], bfr, acc[m][c], 0, 0, 0);
            }
        }
        __syncthreads();
    }
    #pragma unroll
    for (int c = 0; c < 2; ++c) {
        int j = j0 + ng * 32 + c * 16 + lx;
        if (j < N) {
            float bv = bias[j];
            #pragma unroll
            for (int m = 0; m < 4; ++m) {
                #pragma unroll
                for (int reg = 0; reg < 4; ++reg) {
                    int b = b0 + mg * 64 + m * 16 + quad * 4 + reg;
                    out[(size_t)b * N + j] = acc[m][c][reg] + bv;
                }
            }
        }
    }
}

// ---------------------------------------------------------------------------
__global__ __launch_bounds__(256) void k_cell(
    const float* __restrict__ sums, const float* __restrict__ prev_c,
    float* __restrict__ next_c, float* __restrict__ next_h)
{
    int idx = blockIdx.x * 256 + threadIdx.x;
    int b = idx >> 9;
    int j = idx & 511;
    const float* srow = sums + (size_t)b * cH4;
    float ig = 1.f / (1.f + __expf(-srow[j]));
    float fg = 1.f / (1.f + __expf(-srow[cR + j]));
    float og = 1.f / (1.f + __expf(-srow[2 * cR + j]));
    float gt = tanh_f(srow[3 * cR + j]);
    float c = fg * prev_c[idx] + ig * gt;
    float hh = og * tanh_f(c);
    next_c[idx] = c;
    next_h[idx] = hh;
}

__global__ __launch_bounds__(256) void k_logsoftmax(float* __restrict__ logits)
{
    __shared__ float red[256];
    int b = blockIdx.x, t = threadIdx.x;
    float* row = logits + (size_t)b * cV;
    const float4* row4 = (const float4*)row;
    float mx = -INFINITY;
    for (int v = t; v < cV / 4; v += 256) {
        float4 f = row4[v];
        mx = fmaxf(mx, fmaxf(fmaxf(f.x, f.y), fmaxf(f.z, f.w)));
    }
    red[t] = mx; __syncthreads();
    for (int off = 128; off > 0; off >>= 1) {
        if (t < off) red[t] = fmaxf(red[t], red[t + off]);
        __syncthreads();
    }
    mx = red[0]; __syncthreads();
    float sum = 0.f;
    for (int v = t; v < cV / 4; v += 256) {
        float4 f = row4[v];
        sum += __expf(f.x - mx) + __expf(f.y - mx) + __expf(f.z - mx) + __expf(f.w - mx);
    }
    red[t] = sum; __syncthreads();
    for (int off = 128; off > 0; off >>= 1) {
        if (t < off) red[t] += red[t + off];
        __syncthreads();
    }
    float lse = mx + logf(red[0]);
    for (int v = t; v < cV / 4; v += 256) {
        float4 f = row4[v];
        f.x -= lse; f.y -= lse; f.z -= lse; f.w -= lse;
        ((float4*)row)[v] = f;
    }
}

// ---------------------------------------------------------------------------
extern "C" void kernel_launch(void* const* d_in, const int* in_sizes, int n_in,
                              void* d_out, int out_size, void* d_ws, size_t ws_size,
                              hipStream_t stream)
{
    const float* x      = (const float*)d_in[0];
    const float* att    = (const float*)d_in[1];
    const float* prev_c = (const float*)d_in[2];
    const float* prev_h = (const float*)d_in[3];
    const float* W_a2a  = (const float*)d_in[4];
    const float* b_a2a  = (const float*)d_in[5];
    const float* W_h2a  = (const float*)d_in[6];
    const float* b_h2a  = (const float*)d_in[7];
    const float* W_d2d  = (const float*)d_in[8];
    const float* b_d2d  = (const float*)d_in[9];
    const float* W_i2h  = (const float*)d_in[10];
    const float* b_i2h  = (const float*)d_in[11];
    const float* W_a2h  = (const float*)d_in[12];
    const float* b_a2h  = (const float*)d_in[13];
    const float* W_h2h  = (const float*)d_in[14];
    const float* b_h2h  = (const float*)d_in[15];
    const float* W_a2a1 = (const float*)d_in[16];
    const float* b_a2a1 = (const float*)d_in[17];
    const float* W_h2a1 = (const float*)d_in[18];
    const float* b_h2a1 = (const float*)d_in[19];
    const float* W_d2d1 = (const float*)d_in[20];
    const float* b_d2d1 = (const float*)d_in[21];
    const float* W_proj = (const float*)d_in[22];
    const float* b_proj = (const float*)d_in[23];

    float* out_next_c = (float*)d_out;                   // B*R
    float* out_top_h  = out_next_c + (size_t)cB * cR;    // B*R
    float* out_logits = out_top_h  + (size_t)cB * cR;    // B*V

    const size_t ATT_FLOATS = 12845056;   // 25,690,112 bf16
    const size_t NEED_A = (ATT_FLOATS + 1445888) * sizeof(float);
    bool bigws = ws_size >= NEED_A;

    float* ws = (float*)d_ws;
    unsigned short* att_bf = (unsigned short*)ws;         // path A only
    float* p = bigws ? (ws + ATT_FLOATS) : ws;
    unsigned short* wa2a_bf  = (unsigned short*)p;  p += 50176;
    unsigned short* wa2a1_bf = (unsigned short*)p;  p += 50176;
    unsigned short* x_bf     = (unsigned short*)p;  p += 65536;
    unsigned short* h_bf     = (unsigned short*)p;  p += 65536;
    unsigned short* ar1_bf   = (unsigned short*)p;  p += 65536;
    unsigned short* ar2_bf   = (unsigned short*)p;  p += 65536;
    unsigned short* toph_bf  = (unsigned short*)p;  p += 65536;
    float* ws_ah      = p;  p += 50176;
    float* ws_scores  = p;  p += 50176;
    float* ws_attres1 = p;  p += 131072;
    float* ws_attres2 = p;  p += 131072;
    float* ws_sums    = p;  p += 524288;
    float* ws_next_h  = p;  p += 131072;

    // ---- small bf16 conversions + attend-1 ah, one launch ----
    k_cvt_ah<<<452 + cB, 256, 0, stream>>>(W_a2a, wa2a_bf, 98,
                                           W_a2a1, wa2a1_bf, 98,
                                           x, x_bf, 128,
                                           prev_h, h_bf, 128,
                                           prev_h, W_h2a, b_h2a, ws_ah);

    // ---- attend 1 (prev_h); fused att fp32->bf16 writeback on path A ----
    k_scores_cv<<<(cB * cA) / 128, 256, 0, stream>>>(att, att_bf, wa2a_bf,
                                                     b_a2a, W_d2d, b_d2d,
                                                     ws_ah, ws_scores,
                                                     bigws ? 1 : 0);
    if (bigws)
        k_attres_bf<<<cB, 256, 0, stream>>>(ws_scores, att_bf, nullptr,
                                            ws_attres1, ar1_bf);
    else
        k_attres_f32<<<cB, 256, 0, stream>>>(ws_scores, att, nullptr,
                                             ws_attres1, ar1_bf);

    // ---- gates + LSTM cell ----
    k_sums<<<dim3(8, 32), 256, 0, stream>>>(x_bf, h_bf, ar1_bf,
                                            W_i2h, W_h2h, W_a2h,
                                            b_i2h, b_h2h, b_a2h, ws_sums);
    k_cell<<<(cB * cR) / 256, 256, 0, stream>>>(ws_sums, prev_c, out_next_c, ws_next_h);

    // ---- attend 2 (next_h); fused top_h = attres2 + next_h ----
    k_ah<<<cB, 256, 0, stream>>>(ws_next_h, W_h2a1, b_h2a1, ws_ah);
    if (bigws) {
        k_scores_bf<<<(cB * cA) / 128, 256, 0, stream>>>(att_bf, wa2a1_bf,
                                                         b_a2a1, W_d2d1, b_d2d1,
                                                         ws_ah, ws_scores);
        k_attres_bf<<<cB, 256, 0, stream>>>(ws_scores, att_bf, ws_next_h,
                                            out_top_h, toph_bf);
    } else {
        k_scores_cv<<<(cB * cA) / 128, 256, 0, stream>>>(att, att_bf, wa2a1_bf,
                                                         b_a2a1, W_d2d1, b_d2d1,
                                                         ws_ah, ws_scores, 0);
        k_attres_f32<<<cB, 256, 0, stream>>>(ws_scores, att, ws_next_h,
                                             out_top_h, toph_bf);
    }

    // ---- projection + log_softmax ----
    k_lin<<<dim3(2, 157), 256, 0, stream>>>(toph_bf, W_proj, b_proj, out_logits, cV);
    k_logsoftmax<<<cB, 256, 0, stream>>>(out_logits);
}

// Round 5
// 356.950 us; speedup vs baseline: 1.4148x; 1.0153x over previous
//
#include <hip/hip_runtime.h>
#include <math.h>

constexpr int cB  = 256;
constexpr int cI  = 512;
constexpr int cR  = 512;
constexpr int cA  = 196;
constexpr int cV  = 10000;
constexpr int cH4 = 2048;   // 4*R
constexpr int AV2_LD = 200; // av2 row stride (196 used, 16B-aligned rows)

typedef short bf16x8 __attribute__((ext_vector_type(8)));
typedef float f32x4  __attribute__((ext_vector_type(4)));
typedef unsigned short us8 __attribute__((ext_vector_type(8)));

__device__ inline unsigned short f2bf(float f) {
    unsigned int u = __float_as_uint(f);
    u += 0x7fffu + ((u >> 16) & 1u);
    return (unsigned short)(u >> 16);
}
__device__ inline float bf2f(unsigned short s) {
    return __uint_as_float(((unsigned int)s) << 16);
}
// fast tanh: 1 - 2/(1+e^{2x}); exact at +-inf, ~1e-7 rel err, v_exp-based
__device__ inline float tanh_f(float x) {
    return 1.f - 2.f / (1.f + __expf(2.f * x));
}

// ---------------------------------------------------------------------------
// k_cvt_ah: four fp32->bf16 conversions (452 blocks) + attend-1 "ah" GEMV
// (256 blocks) in ONE launch.
// ---------------------------------------------------------------------------
__global__ __launch_bounds__(256) void k_cvt_ah(
    const float* __restrict__ s0, unsigned short* __restrict__ d0, int nb0,
    const float* __restrict__ s1, unsigned short* __restrict__ d1, int nb1,
    const float* __restrict__ s2, unsigned short* __restrict__ d2, int nb2,
    const float* __restrict__ s3, unsigned short* __restrict__ d3, int nb3,
    const float* __restrict__ h, const float* __restrict__ W,
    const float* __restrict__ bias, float* __restrict__ outah)
{
    __shared__ __align__(16) float h_s[cR];
    int blk = blockIdx.x;
    int ncvt = nb0 + nb1 + nb2 + nb3;
    int t = threadIdx.x;
    if (blk < ncvt) {
        const float* src; unsigned short* dst; int base;
        if (blk < nb0)                  { src = s0; dst = d0; base = blk; }
        else if (blk < nb0 + nb1)       { src = s1; dst = d1; base = blk - nb0; }
        else if (blk < nb0 + nb1 + nb2) { src = s2; dst = d2; base = blk - nb0 - nb1; }
        else                            { src = s3; dst = d3; base = blk - nb0 - nb1 - nb2; }
        int i = base * 256 + t;
        float4 v = ((const float4*)src)[i];
        ushort4 b;
        b.x = f2bf(v.x); b.y = f2bf(v.y); b.z = f2bf(v.z); b.w = f2bf(v.w);
        ((ushort4*)dst)[i] = b;
    } else {
        int b = blk - ncvt;
        h_s[t]       = h[b * cR + t];
        h_s[t + 256] = h[b * cR + t + 256];
        __syncthreads();
        if (t < cA) {
            const float4* Wv = (const float4*)(W + (size_t)t * cR);
            const float4* hv = (const float4*)h_s;
            float acc = 0.f;
            #pragma unroll 4
            for (int k = 0; k < cR / 4; ++k) {
                float4 w4 = Wv[k], x4 = hv[k];
                acc += w4.x * x4.x + w4.y * x4.y + w4.z * x4.z + w4.w * x4.w;
            }
            outah[b * cA + t] = acc + bias[t];
        }
    }
}

// ---------------------------------------------------------------------------
// k_ah: fallback standalone GEMV.
// ---------------------------------------------------------------------------
__global__ __launch_bounds__(256) void k_ah(
    const float* __restrict__ h, const float* __restrict__ W,
    const float* __restrict__ bias, float* __restrict__ out)
{
    __shared__ __align__(16) float h_s[cR];
    int b = blockIdx.x;
    int t = threadIdx.x;
    h_s[t]       = h[b * cR + t];
    h_s[t + 256] = h[b * cR + t + 256];
    __syncthreads();
    if (t < cA) {
        const float4* Wv = (const float4*)(W + (size_t)t * cR);
        const float4* hv = (const float4*)h_s;
        float acc = 0.f;
        #pragma unroll 4
        for (int k = 0; k < cR / 4; ++k) {
            float4 w4 = Wv[k], x4 = hv[k];
            acc += w4.x * x4.x + w4.y * x4.y + w4.z * x4.z + w4.w * x4.w;
        }
        out[b * cA + t] = acc + bias[t];
    }
}

constexpr int SC_LDA = 72;   // bf16 elems per LDS row (144 B, 2-way alias free)

// ---------------------------------------------------------------------------
// k_scores2g (ROUND-5): merged double-GEMM. Key algebra: attend-2's GEMM
// av2 = att @ W_a2a1^T does NOT depend on next_h (only the ah2 term inside
// the tanh does). So one kernel stages att ONCE and computes BOTH 196-col
// GEMMs: cols 0-223 = W_a2a (-> scores1 via tanh.wd epilogue), cols 224-447
// = W_a2a1 (-> av2+ba2 stored bf16, consumed later by k_dot2). Deletes the
// entire k_scores_bf (~55us att_bf re-read kernel). 512 thr = 8 waves
// (2 row-groups x 4 col-groups) -> per-SIMD work per K-step identical to the
// old 2-co-resident-block scores_cv. LDS ~87KB -> 1 block/CU.
// ---------------------------------------------------------------------------
__global__ __launch_bounds__(512, 2) void k_scores2g(
    const float* __restrict__ att, unsigned short* __restrict__ att_bf,
    const unsigned short* __restrict__ wa1_bf,
    const unsigned short* __restrict__ wa2_bf,
    const float* __restrict__ ba1, const float* __restrict__ ba2,
    const float* __restrict__ Wd1, const float* __restrict__ bd1,
    const float* __restrict__ ah, float* __restrict__ scores,
    unsigned short* __restrict__ av2)
{
    __shared__ __align__(16) unsigned short att_s[128][SC_LDA];
    __shared__ __align__(16) unsigned short wa_s[448][SC_LDA];
    __shared__ float ba1_s[224];
    __shared__ float ba2_s[224];
    __shared__ float wd_s[224];
    __shared__ float part_s[128][2];

    int tid  = threadIdx.x;
    int wave = tid >> 6;
    int lane = tid & 63;
    int lx   = lane & 15;
    int quad = lane >> 4;
    int mg   = wave >> 2;          // 0..1: rows mg*64 .. +63
    int ng   = wave & 3;           // 0..3: cols ng*112 .. +111 (of 448)
    size_t row0 = (size_t)blockIdx.x * 128;

    if (tid < 224) {
        ba1_s[tid] = (tid < cA) ? ba1[tid] : 0.f;
        ba2_s[tid] = (tid < cA) ? ba2[tid] : 0.f;
        wd_s[tid]  = (tid < cA) ? Wd1[tid] : 0.f;
    }

    int a_r = tid >> 4, a_c = (tid & 15) * 4;   // att: rows a_r+32i, i<4
    int w_r = tid >> 3, w_c = (tid & 7) * 8;    // wa : rows w_r+64i, i<7
    const float* attA = att + (row0 + a_r) * cR + a_c;
    unsigned short* wbA = att_bf + (row0 + a_r) * cR + a_c;

    f32x4 acc[4][7];
    #pragma unroll
    for (int m = 0; m < 4; ++m)
        #pragma unroll
        for (int c = 0; c < 7; ++c) acc[m][c] = (f32x4){0.f, 0.f, 0.f, 0.f};

    float4 patt[4];
    us8    pwa[7];
    #pragma unroll
    for (int i = 0; i < 4; ++i)
        patt[i] = *(const float4*)(attA + (size_t)i * 32 * cR);
    #pragma unroll
    for (int i = 0; i < 7; ++i) {
        int R = w_r + 64 * i;
        const unsigned short* src = (R < 224) ? wa1_bf : wa2_bf;
        int rr = (R < 224) ? R : R - 224;
        pwa[i] = (rr < cA) ? *(const us8*)(src + (size_t)rr * cR + w_c)
                           : (us8){0,0,0,0,0,0,0,0};
    }

    for (int k0 = 0; k0 < cR; k0 += 64) {
        #pragma unroll
        for (int i = 0; i < 4; ++i) {
            float4 v = patt[i];
            ushort4 bv;
            bv.x = f2bf(v.x); bv.y = f2bf(v.y); bv.z = f2bf(v.z); bv.w = f2bf(v.w);
            *(ushort4*)&att_s[a_r + 32 * i][a_c] = bv;
            *(ushort4*)(wbA + (size_t)i * 32 * cR + k0) = bv;
        }
        #pragma unroll
        for (int i = 0; i < 7; ++i)
            *(us8*)&wa_s[w_r + 64 * i][w_c] = pwa[i];
        if (k0 + 64 < cR) {
            #pragma unroll
            for (int i = 0; i < 4; ++i)
                patt[i] = *(const float4*)(attA + (size_t)i * 32 * cR + k0 + 64);
            #pragma unroll
            for (int i = 0; i < 7; ++i) {
                int R = w_r + 64 * i;
                const unsigned short* src = (R < 224) ? wa1_bf : wa2_bf;
                int rr = (R < 224) ? R : R - 224;
                pwa[i] = (rr < cA) ? *(const us8*)(src + (size_t)rr * cR + k0 + 64 + w_c)
                                   : (us8){0,0,0,0,0,0,0,0};
            }
        }
        __syncthreads();
        #pragma unroll
        for (int ks = 0; ks < 2; ++ks) {
            int kb = ks * 32 + quad * 8;
            bf16x8 af[4];
            #pragma unroll
            for (int m = 0; m < 4; ++m)
                af[m] = *(const bf16x8*)&att_s[mg * 64 + m * 16 + lx][kb];
            #pragma unroll
            for (int c = 0; c < 7; ++c) {
                bf16x8 bfr = *(const bf16x8*)&wa_s[ng * 112 + c * 16 + lx][kb];
                #pragma unroll
                for (int m = 0; m < 4; ++m)
                    acc[m][c] = __builtin_amdgcn_mfma_f32_16x16x32_bf16(af[m], bfr, acc[m][c], 0, 0, 0);
            }
        }
        __syncthreads();
    }

    // epilogue: ng<2 -> scores1 (tanh.wd + cross-wave reduce);
    //           ng>=2 -> av2 store (+ba2, bf16), zero pad cols 196..199.
    if (ng < 2) {
        #pragma unroll
        for (int m = 0; m < 4; ++m) {
            #pragma unroll
            for (int reg = 0; reg < 4; ++reg) {
                int rl = mg * 64 + m * 16 + quad * 4 + reg;
                float ahv = ah[row0 + rl];
                float part = 0.f;
                #pragma unroll
                for (int c = 0; c < 7; ++c) {
                    int col = ng * 112 + c * 16 + lx;
                    part += tanh_f(acc[m][c][reg] + ba1_s[col] + ahv) * wd_s[col];
                }
                part += __shfl_xor(part, 1);
                part += __shfl_xor(part, 2);
                part += __shfl_xor(part, 4);
                part += __shfl_xor(part, 8);
                if (lx == 0) part_s[rl][ng] = part;
            }
        }
    } else {
        int cb = (ng - 2) * 112;
        #pragma unroll
        for (int m = 0; m < 4; ++m) {
            #pragma unroll
            for (int reg = 0; reg < 4; ++reg) {
                int rl = mg * 64 + m * 16 + quad * 4 + reg;
                size_t ro = (size_t)(row0 + rl) * AV2_LD;
                #pragma unroll
                for (int c = 0; c < 7; ++c) {
                    int col = cb + c * 16 + lx;
                    float v = acc[m][c][reg] + ba2_s[col];
                    if (col < cA)          av2[ro + col] = f2bf(v);
                    else if (col < AV2_LD) av2[ro + col] = 0;
                }
            }
        }
    }
    __syncthreads();
    if (tid < 128)
        scores[row0 + tid] = part_s[tid][0] + part_s[tid][1] + bd1[0];
}

// ---------------------------------------------------------------------------
// k_dot2: attend-2 scores from precomputed av2. scores[r] =
// bd + sum_col tanh(av2[r,col] + ah2[b,col]) * wd[col].  8 rows/block
// (4 waves x 2 half-waves), 25 lanes x us8 = 200 cols coalesced per row.
// ---------------------------------------------------------------------------
__global__ __launch_bounds__(256) void k_dot2(
    const unsigned short* __restrict__ av2, const float* __restrict__ ah,
    const float* __restrict__ Wd, const float* __restrict__ bd,
    float* __restrict__ scores)
{
    __shared__ float wd_s[AV2_LD];
    int t = threadIdx.x;
    if (t < AV2_LD) wd_s[t] = (t < cA) ? Wd[t] : 0.f;
    __syncthreads();
    int wave = t >> 6, half = (t >> 5) & 1, L = t & 31;
    int r = blockIdx.x * 8 + wave * 2 + half;
    int b = r / cA;
    float s = 0.f;
    if (L < 25) {
        us8 v = *(const us8*)(av2 + (size_t)r * AV2_LD + L * 8);
        const float* ap = ah + (size_t)b * cA + L * 8;
        float4 a0 = *(const float4*)(ap);
        float4 a1 = (L < 24) ? *(const float4*)(ap + 4)
                             : make_float4(0.f, 0.f, 0.f, 0.f);
        float av[8] = {a0.x, a0.y, a0.z, a0.w, a1.x, a1.y, a1.z, a1.w};
        #pragma unroll
        for (int j = 0; j < 8; ++j)
            s += tanh_f(bf2f(v[j]) + av[j]) * wd_s[L * 8 + j];
    }
    s += __shfl_xor(s, 1);
    s += __shfl_xor(s, 2);
    s += __shfl_xor(s, 4);
    s += __shfl_xor(s, 8);
    s += __shfl_xor(s, 16);
    if (L == 0) scores[r] = s + bd[0];
}

// ---------------------------------------------------------------------------
// FALLBACK scores kernels (R4 structure, kept for smaller workspaces).
// ---------------------------------------------------------------------------
__global__ __launch_bounds__(256, 2) void k_scores_cv(
    const float* __restrict__ att, unsigned short* __restrict__ att_bf,
    const unsigned short* __restrict__ wa_bf,
    const float* __restrict__ ba, const float* __restrict__ Wd,
    const float* __restrict__ bd, const float* __restrict__ ah,
    float* __restrict__ scores, int wb)
{
    __shared__ __align__(16) unsigned short att_s[128][SC_LDA];
    __shared__ __align__(16) unsigned short wa_s[224][SC_LDA];
    __shared__ float ba_s[224];
    __shared__ float wd_s[224];
    __shared__ float part_s[128][2];

    int tid  = threadIdx.x;
    int wave = tid >> 6;
    int lane = tid & 63;
    int lx   = lane & 15;
    int quad = lane >> 4;
    int mg   = wave >> 1;
    int ng   = wave & 1;
    size_t row0 = (size_t)blockIdx.x * 128;

    if (tid < 224) {
        ba_s[tid] = (tid < cA) ? ba[tid] : 0.f;
        wd_s[tid] = (tid < cA) ? Wd[tid] : 0.f;
    }

    int a_r = tid >> 4, a_c = (tid & 15) * 4;
    int w_r = tid >> 3, w_c = (tid & 7) * 8;
    const float* attA = att + (row0 + a_r) * cR + a_c;
    unsigned short* wbA = att_bf + (row0 + a_r) * cR + a_c;

    f32x4 acc[4][7];
    #pragma unroll
    for (int m = 0; m < 4; ++m)
        #pragma unroll
        for (int c = 0; c < 7; ++c) acc[m][c] = (f32x4){0.f, 0.f, 0.f, 0.f};

    float4 patt[8];
    us8    pwa[7];
    #pragma unroll
    for (int i = 0; i < 8; ++i)
        patt[i] = *(const float4*)(attA + (size_t)i * 16 * cR);
    #pragma unroll
    for (int i = 0; i < 7; ++i) {
        int r = w_r + 32 * i;
        pwa[i] = (r < cA) ? *(const us8*)(wa_bf + (size_t)r * cR + w_c)
                          : (us8){0,0,0,0,0,0,0,0};
    }

    for (int k0 = 0; k0 < cR; k0 += 64) {
        #pragma unroll
        for (int i = 0; i < 8; ++i) {
            float4 v = patt[i];
            ushort4 bv;
            bv.x = f2bf(v.x); bv.y = f2bf(v.y); bv.z = f2bf(v.z); bv.w = f2bf(v.w);
            *(ushort4*)&att_s[a_r + 16 * i][a_c] = bv;
            if (wb)
                *(ushort4*)(wbA + (size_t)i * 16 * cR + k0) = bv;
        }
        #pragma unroll
        for (int i = 0; i < 7; ++i)
            *(us8*)&wa_s[w_r + 32 * i][w_c] = pwa[i];
        if (k0 + 64 < cR) {
            #pragma unroll
            for (int i = 0; i < 8; ++i)
                patt[i] = *(const float4*)(attA + (size_t)i * 16 * cR + k0 + 64);
            #pragma unroll
            for (int i = 0; i < 7; ++i) {
                int r = w_r + 32 * i;
                pwa[i] = (r < cA) ? *(const us8*)(wa_bf + (size_t)r * cR + k0 + 64 + w_c)
                                  : (us8){0,0,0,0,0,0,0,0};
            }
        }
        __syncthreads();
        #pragma unroll
        for (int ks = 0; ks < 2; ++ks) {
            int kb = ks * 32 + quad * 8;
            bf16x8 af[4];
            #pragma unroll
            for (int m = 0; m < 4; ++m)
                af[m] = *(const bf16x8*)&att_s[mg * 64 + m * 16 + lx][kb];
            #pragma unroll
            for (int c = 0; c < 7; ++c) {
                bf16x8 bfr = *(const bf16x8*)&wa_s[ng * 112 + c * 16 + lx][kb];
                #pragma unroll
                for (int m = 0; m < 4; ++m)
                    acc[m][c] = __builtin_amdgcn_mfma_f32_16x16x32_bf16(af[m], bfr, acc[m][c], 0, 0, 0);
            }
        }
        __syncthreads();
    }

    #pragma unroll
    for (int m = 0; m < 4; ++m) {
        #pragma unroll
        for (int reg = 0; reg < 4; ++reg) {
            int rl = mg * 64 + m * 16 + quad * 4 + reg;
            float ahv = ah[row0 + rl];
            float part = 0.f;
            #pragma unroll
            for (int c = 0; c < 7; ++c) {
                int col = ng * 112 + c * 16 + lx;
                part += tanh_f(acc[m][c][reg] + ba_s[col] + ahv) * wd_s[col];
            }
            part += __shfl_xor(part, 1);
            part += __shfl_xor(part, 2);
            part += __shfl_xor(part, 4);
            part += __shfl_xor(part, 8);
            if (lx == 0) part_s[rl][ng] = part;
        }
    }
    __syncthreads();
    if (tid < 128)
        scores[row0 + tid] = part_s[tid][0] + part_s[tid][1] + bd[0];
}

__global__ __launch_bounds__(256, 2) void k_scores_bf(
    const unsigned short* __restrict__ att_bf,
    const unsigned short* __restrict__ wa_bf,
    const float* __restrict__ ba, const float* __restrict__ Wd,
    const float* __restrict__ bd, const float* __restrict__ ah,
    float* __restrict__ scores)
{
    __shared__ __align__(16) unsigned short att_s[128][SC_LDA];
    __shared__ __align__(16) unsigned short wa_s[224][SC_LDA];
    __shared__ float ba_s[224];
    __shared__ float wd_s[224];
    __shared__ float part_s[128][2];

    int tid  = threadIdx.x;
    int wave = tid >> 6;
    int lane = tid & 63;
    int lx   = lane & 15;
    int quad = lane >> 4;
    int mg   = wave >> 1;
    int ng   = wave & 1;
    size_t row0 = (size_t)blockIdx.x * 128;

    if (tid < 224) {
        ba_s[tid] = (tid < cA) ? ba[tid] : 0.f;
        wd_s[tid] = (tid < cA) ? Wd[tid] : 0.f;
    }

    int a_r = tid >> 3, a_c = (tid & 7) * 8;
    int w_r = tid >> 3, w_c = (tid & 7) * 8;
    const unsigned short* attA = att_bf + (row0 + a_r) * cR + a_c;

    f32x4 acc[4][7];
    #pragma unroll
    for (int m = 0; m < 4; ++m)
        #pragma unroll
        for (int c = 0; c < 7; ++c) acc[m][c] = (f32x4){0.f, 0.f, 0.f, 0.f};

    us8 patt[4];
    us8 pwa[7];
    #pragma unroll
    for (int i = 0; i < 4; ++i)
        patt[i] = *(const us8*)(attA + (size_t)i * 32 * cR);
    #pragma unroll
    for (int i = 0; i < 7; ++i) {
        int r = w_r + 32 * i;
        pwa[i] = (r < cA) ? *(const us8*)(wa_bf + (size_t)r * cR + w_c)
                          : (us8){0,0,0,0,0,0,0,0};
    }

    for (int k0 = 0; k0 < cR; k0 += 64) {
        #pragma unroll
        for (int i = 0; i < 4; ++i)
            *(us8*)&att_s[a_r + 32 * i][a_c] = patt[i];
        #pragma unroll
        for (int i = 0; i < 7; ++i)
            *(us8*)&wa_s[w_r + 32 * i][w_c] = pwa[i];
        if (k0 + 64 < cR) {
            #pragma unroll
            for (int i = 0; i < 4; ++i)
                patt[i] = *(const us8*)(attA + (size_t)i * 32 * cR + k0 + 64);
            #pragma unroll
            for (int i = 0; i < 7; ++i) {
                int r = w_r + 32 * i;
                pwa[i] = (r < cA) ? *(const us8*)(wa_bf + (size_t)r * cR + k0 + 64 + w_c)
                                  : (us8){0,0,0,0,0,0,0,0};
            }
        }
        __syncthreads();
        #pragma unroll
        for (int ks = 0; ks < 2; ++ks) {
            int kb = ks * 32 + quad * 8;
            bf16x8 af[4];
            #pragma unroll
            for (int m = 0; m < 4; ++m)
                af[m] = *(const bf16x8*)&att_s[mg * 64 + m * 16 + lx][kb];
            #pragma unroll
            for (int c = 0; c < 7; ++c) {
                bf16x8 bfr = *(const bf16x8*)&wa_s[ng * 112 + c * 16 + lx][kb];
                #pragma unroll
                for (int m = 0; m < 4; ++m)
                    acc[m][c] = __builtin_amdgcn_mfma_f32_16x16x32_bf16(af[m], bfr, acc[m][c], 0, 0, 0);
            }
        }
        __syncthreads();
    }

    #pragma unroll
    for (int m = 0; m < 4; ++m) {
        #pragma unroll
        for (int reg = 0; reg < 4; ++reg) {
            int rl = mg * 64 + m * 16 + quad * 4 + reg;
            float ahv = ah[row0 + rl];
            float part = 0.f;
            #pragma unroll
            for (int c = 0; c < 7; ++c) {
                int col = ng * 112 + c * 16 + lx;
                part += tanh_f(acc[m][c][reg] + ba_s[col] + ahv) * wd_s[col];
            }
            part += __shfl_xor(part, 1);
            part += __shfl_xor(part, 2);
            part += __shfl_xor(part, 4);
            part += __shfl_xor(part, 8);
            if (lx == 0) part_s[rl][ng] = part;
        }
    }
    __syncthreads();
    if (tid < 128)
        scores[row0 + tid] = part_s[tid][0] + part_s[tid][1] + bd[0];
}

// ---------------------------------------------------------------------------
// softmax helper (256-thread LDS reduce over A scores)
// ---------------------------------------------------------------------------
__device__ inline void softmax_w(const float* scores, int b, int t, float* red,
                                 float* w_s)
{
    float s = (t < cA) ? scores[b * cA + t] : -INFINITY;
    red[t] = s; __syncthreads();
    for (int off = 128; off > 0; off >>= 1) {
        if (t < off) red[t] = fmaxf(red[t], red[t + off]);
        __syncthreads();
    }
    float mx = red[0];
    __syncthreads();
    float e = (t < cA) ? __expf(s - mx) : 0.f;
    red[t] = e; __syncthreads();
    for (int off = 128; off > 0; off >>= 1) {
        if (t < off) red[t] += red[t + off];
        __syncthreads();
    }
    float inv = 1.f / red[0];
    if (t < cA) w_s[t] = e * inv;
    __syncthreads();
}

// ---------------------------------------------------------------------------
// k_attres_bf: softmax + weighted sum (+ optional addin). 512 threads:
// grid is 256 blocks = 1 block/CU, so TLP comes from block size (8 waves).
// ---------------------------------------------------------------------------
__global__ __launch_bounds__(512) void k_attres_bf(
    const float* __restrict__ scores, const unsigned short* __restrict__ att_bf,
    const float* __restrict__ addin,
    float* __restrict__ out, unsigned short* __restrict__ out_bf)
{
    __shared__ float red[512];
    __shared__ float w_s[cA];
    __shared__ float red2[8][512];
    int b = blockIdx.x, t = threadIdx.x;

    float s = (t < cA) ? scores[b * cA + t] : -INFINITY;
    red[t] = s; __syncthreads();
    for (int off = 256; off > 0; off >>= 1) {
        if (t < off) red[t] = fmaxf(red[t], red[t + off]);
        __syncthreads();
    }
    float mx = red[0];
    __syncthreads();
    float e = (t < cA) ? __expf(s - mx) : 0.f;
    red[t] = e; __syncthreads();
    for (int off = 256; off > 0; off >>= 1) {
        if (t < off) red[t] += red[t + off];
        __syncthreads();
    }
    float inv = 1.f / red[0];
    if (t < cA) w_s[t] = e * inv;
    __syncthreads();

    int p = t >> 6, l = t & 63;
    const unsigned short* base = att_bf + (size_t)b * cA * cR + l * 8;
    float acc[8] = {};
    #pragma unroll 4
    for (int a = p; a < cA; a += 8) {
        us8 v = *(const us8*)(base + (size_t)a * cR);
        float w = w_s[a];
        #pragma unroll
        for (int j = 0; j < 8; ++j)
            acc[j] += bf2f(v[j]) * w;
    }
    #pragma unroll
    for (int j = 0; j < 8; ++j)
        red2[p][l * 8 + j] = acc[j];
    __syncthreads();
    {
        int r = t;
        float s2 = red2[0][r] + red2[1][r] + red2[2][r] + red2[3][r]
                 + red2[4][r] + red2[5][r] + red2[6][r] + red2[7][r];
        if (addin) s2 += addin[b * cR + r];
        out[b * cR + r] = s2;
        out_bf[b * cR + r] = f2bf(s2);
    }
}

// fallback (small ws): fp32 att
__global__ __launch_bounds__(256) void k_attres_f32(
    const float* __restrict__ scores, const float* __restrict__ att,
    const float* __restrict__ addin,
    float* __restrict__ out, unsigned short* __restrict__ out_bf)
{
    __shared__ float red[256];
    __shared__ float w_s[cA];
    int b = blockIdx.x, t = threadIdx.x;
    softmax_w(scores, b, t, red, w_s);

    const float* attb = att + (size_t)b * cA * cR + 2 * t;
    float acc0 = 0.f, acc1 = 0.f;
    #pragma unroll 4
    for (int a = 0; a < cA; ++a) {
        float2 u = *(const float2*)(attb + (size_t)a * cR);
        float w = w_s[a];
        acc0 += u.x * w;
        acc1 += u.y * w;
    }
    if (addin) {
        acc0 += addin[b * cR + 2 * t];
        acc1 += addin[b * cR + 2 * t + 1];
    }
    out[b * cR + 2 * t]     = acc0;
    out[b * cR + 2 * t + 1] = acc1;
    out_bf[b * cR + 2 * t]     = f2bf(acc0);
    out_bf[b * cR + 2 * t + 1] = f2bf(acc1);
}

// ---------------------------------------------------------------------------
// k_sums: sums[b,j] = bi+bh+ba + x.Wi + h.Wh + ar.Wa. Tile 32x64,
// grid (8,32), pipelined, __syncthreads.
// ---------------------------------------------------------------------------
__global__ __launch_bounds__(256, 4) void k_sums(
    const unsigned short* __restrict__ x_bf,
    const unsigned short* __restrict__ h_bf,
    const unsigned short* __restrict__ ar_bf,
    const float* __restrict__ Wi, const float* __restrict__ Wh,
    const float* __restrict__ Wa,
    const float* __restrict__ bi, const float* __restrict__ bh,
    const float* __restrict__ ba, float* __restrict__ out)
{
    __shared__ __align__(16) unsigned short a_s[32][SC_LDA];
    __shared__ __align__(16) unsigned short w_s[64][SC_LDA];
    int tid  = threadIdx.x;
    int wave = tid >> 6;
    int lane = tid & 63;
    int lx   = lane & 15;
    int quad = lane >> 4;
    int b0 = blockIdx.x * 32;
    int j0 = blockIdx.y * 64;

    const unsigned short* Aarr[3] = {x_bf, h_bf, ar_bf};
    const float* Warr[3] = {Wi, Wh, Wa};

    int a_r = tid >> 3, a_c = (tid & 7) * 8;
    int w_r = tid >> 4, w_c = (tid & 15) * 4;

    f32x4 acc0 = {0.f, 0.f, 0.f, 0.f}, acc1 = {0.f, 0.f, 0.f, 0.f};

    us8 pa;
    float4 pw[4];
    pa = *(const us8*)(Aarr[0] + (size_t)(b0 + a_r) * cR + a_c);
    #pragma unroll
    for (int i = 0; i < 4; ++i)
        pw[i] = *(const float4*)(Warr[0] + (size_t)(j0 + w_r + 16 * i) * cR + w_c);

    for (int it = 0; it < 24; ++it) {
        *(us8*)&a_s[a_r][a_c] = pa;
        #pragma unroll
        for (int i = 0; i < 4; ++i) {
            float4 v = pw[i];
            ushort4 bv;
            bv.x = f2bf(v.x); bv.y = f2bf(v.y); bv.z = f2bf(v.z); bv.w = f2bf(v.w);
            *(ushort4*)&w_s[w_r + 16 * i][w_c] = bv;
        }
        if (it < 23) {
            int s2 = (it + 1) >> 3, k2 = ((it + 1) & 7) * 64;
            pa = *(const us8*)(Aarr[s2] + (size_t)(b0 + a_r) * cR + k2 + a_c);
            #pragma unroll
            for (int i = 0; i < 4; ++i)
                pw[i] = *(const float4*)(Warr[s2] + (size_t)(j0 + w_r + 16 * i) * cR + k2 + w_c);
        }
        __syncthreads();
        #pragma unroll
        for (int ks = 0; ks < 2; ++ks) {
            int kb = ks * 32 + quad * 8;
            bf16x8 afr0 = *(const bf16x8*)&a_s[lx][kb];
            bf16x8 afr1 = *(const bf16x8*)&a_s[16 + lx][kb];
            bf16x8 bfr  = *(const bf16x8*)&w_s[wave * 16 + lx][kb];
            acc0 = __builtin_amdgcn_mfma_f32_16x16x32_bf16(afr0, bfr, acc0, 0, 0, 0);
            acc1 = __builtin_amdgcn_mfma_f32_16x16x32_bf16(afr1, bfr, acc1, 0, 0, 0);
        }
        __syncthreads();
    }
    int j = j0 + wave * 16 + lx;
    float bsum = bi[j] + bh[j] + ba[j];
    #pragma unroll
    for (int reg = 0; reg < 4; ++reg) {
        int b = b0 + quad * 4 + reg;
        out[(size_t)b * cH4 + j]        = acc0[reg] + bsum;
        out[(size_t)(b + 16) * cH4 + j] = acc1[reg] + bsum;
    }
}

// ---------------------------------------------------------------------------
// k_lin: out[b,j] = bias[j] + in.W[j]. Tile M=128 x N=64, grid (2,157).
// ---------------------------------------------------------------------------
__global__ __launch_bounds__(256, 3) void k_lin(
    const unsigned short* __restrict__ in_bf, const float* __restrict__ W,
    const float* __restrict__ bias, float* __restrict__ out, int N)
{
    __shared__ __align__(16) unsigned short a_s[128][SC_LDA];
    __shared__ __align__(16) unsigned short w_s[64][SC_LDA];
    int tid  = threadIdx.x;
    int wave = tid >> 6;
    int lane = tid & 63;
    int lx   = lane & 15;
    int quad = lane >> 4;
    int mg   = wave >> 1;
    int ng   = wave & 1;
    int b0 = blockIdx.x * 128;
    int j0 = blockIdx.y * 64;

    int a_r = tid >> 3, a_c = (tid & 7) * 8;
    int w_r = tid >> 4, w_c = (tid & 15) * 4;

    f32x4 acc[4][2];
    #pragma unroll
    for (int m = 0; m < 4; ++m)
        #pragma unroll
        for (int c = 0; c < 2; ++c) acc[m][c] = (f32x4){0.f, 0.f, 0.f, 0.f};

    us8 pa[4];
    float4 pw[4];
    #pragma unroll
    for (int i = 0; i < 4; ++i)
        pa[i] = *(const us8*)(in_bf + (size_t)(b0 + a_r + 32 * i) * cR + a_c);
    #pragma unroll
    for (int i = 0; i < 4; ++i) {
        int r = j0 + w_r + 16 * i;
        pw[i] = (r < N) ? *(const float4*)(W + (size_t)r * cR + w_c)
                        : make_float4(0.f, 0.f, 0.f, 0.f);
    }

    for (int k0 = 0; k0 < cR; k0 += 64) {
        #pragma unroll
        for (int i = 0; i < 4; ++i)
            *(us8*)&a_s[a_r + 32 * i][a_c] = pa[i];
        #pragma unroll
        for (int i = 0; i < 4; ++i) {
            float4 v = pw[i];
            ushort4 bv;
            bv.x = f2bf(v.x); bv.y = f2bf(v.y); bv.z = f2bf(v.z); bv.w = f2bf(v.w);
            *(ushort4*)&w_s[w_r + 16 * i][w_c] = bv;
        }
        if (k0 + 64 < cR) {
            #pragma unroll
            for (int i = 0; i < 4; ++i)
                pa[i] = *(const us8*)(in_bf + (size_t)(b0 + a_r + 32 * i) * cR + k0 + 64 + a_c);
            #pragma unroll
            for (int i = 0; i < 4; ++i) {
                int r = j0 + w_r + 16 * i;
                pw[i] = (r < N) ? *(const float4*)(W + (size_t)r * cR + k0 + 64 + w_c)
                                : make_float4(0.f, 0.f, 0.f, 0.f);
            }
        }
        __syncthreads();
        #pragma unroll
        for (int ks = 0; ks < 2; ++ks) {
            int kb = ks * 32 + quad * 8;
            bf16x8 af[4];
            #pragma unroll
            for (int m = 0; m < 4; ++m)
                af[m] = *(const bf16x8*)&a_s[mg * 64 + m * 16 + lx][kb];
            #pragma unroll
            for (int c = 0; c < 2; ++c) {
                bf16x8 bfr = *(const bf16x8*)&w_s[ng * 32 + c * 16 + lx][kb];
                #pragma unroll
                for (int m = 0; m < 4; ++m)
                    acc[m][c] = __builtin_amdgcn_mfma_f32_16x16x32_bf16(af[m], bfr, acc[m][c], 0, 0, 0);
            }
        }
        __syncthreads();
    }
    #pragma unroll
    for (int c = 0; c < 2; ++c) {
        int j = j0 + ng * 32 + c * 16 + lx;
        if (j < N) {
            float bv = bias[j];
            #pragma unroll
            for (int m = 0; m < 4; ++m) {
                #pragma unroll
                for (int reg = 0; reg < 4; ++reg) {
                    int b = b0 + mg * 64 + m * 16 + quad * 4 + reg;
                    out[(size_t)b * N + j] = acc[m][c][reg] + bv;
                }
            }
        }
    }
}

// ---------------------------------------------------------------------------
// k_cell_ah: LSTM cell for one b (512 elems) + attend-2 ah GEMV from LDS.
// Merges k_cell + k_ah (one less launch; next_h read from LDS not HBM).
// ---------------------------------------------------------------------------
__global__ __launch_bounds__(256) void k_cell_ah(
    const float* __restrict__ sums, const float* __restrict__ prev_c,
    const float* __restrict__ W, const float* __restrict__ bias,
    float* __restrict__ next_c, float* __restrict__ next_h,
    float* __restrict__ outah)
{
    __shared__ __align__(16) float h_s[cR];
    int b = blockIdx.x, t = threadIdx.x;
    const float* srow = sums + (size_t)b * cH4;
    #pragma unroll
    for (int rr = 0; rr < 2; ++rr) {
        int j = t + rr * 256;
        float ig = 1.f / (1.f + __expf(-srow[j]));
        float fg = 1.f / (1.f + __expf(-srow[cR + j]));
        float og = 1.f / (1.f + __expf(-srow[2 * cR + j]));
        float gt = tanh_f(srow[3 * cR + j]);
        float c = fg * prev_c[b * cR + j] + ig * gt;
        float h = og * tanh_f(c);
        next_c[b * cR + j] = c;
        next_h[b * cR + j] = h;
        h_s[j] = h;
    }
    __syncthreads();
    if (t < cA) {
        const float4* Wv = (const float4*)(W + (size_t)t * cR);
        const float4* hv = (const float4*)h_s;
        float acc = 0.f;
        #pragma unroll 4
        for (int k = 0; k < cR / 4; ++k) {
            float4 w4 = Wv[k], x4 = hv[k];
            acc += w4.x * x4.x + w4.y * x4.y + w4.z * x4.z + w4.w * x4.w;
        }
        outah[b * cA + t] = acc + bias[t];
    }
}

// fallback standalone cell
__global__ __launch_bounds__(256) void k_cell(
    const float* __restrict__ sums, const float* __restrict__ prev_c,
    float* __restrict__ next_c, float* __restrict__ next_h)
{
    int idx = blockIdx.x * 256 + threadIdx.x;
    int b = idx >> 9;
    int j = idx & 511;
    const float* srow = sums + (size_t)b * cH4;
    float ig = 1.f / (1.f + __expf(-srow[j]));
    float fg = 1.f / (1.f + __expf(-srow[cR + j]));
    float og = 1.f / (1.f + __expf(-srow[2 * cR + j]));
    float gt = tanh_f(srow[3 * cR + j]);
    float c = fg * prev_c[idx] + ig * gt;
    float hh = og * tanh_f(c);
    next_c[idx] = c;
    next_h[idx] = hh;
}

// ---------------------------------------------------------------------------
// k_logsoftmax: online (m,d) single fused pass + write pass (3 -> 2 passes).
// ---------------------------------------------------------------------------
__global__ __launch_bounds__(256) void k_logsoftmax(float* __restrict__ logits)
{
    __shared__ float red_m[256];
    __shared__ float red_d[256];
    int b = blockIdx.x, t = threadIdx.x;
    float* row = logits + (size_t)b * cV;
    const float4* row4 = (const float4*)row;
    float m = -INFINITY, d = 0.f;
    for (int v = t; v < cV / 4; v += 256) {
        float4 f = row4[v];
        float m4 = fmaxf(fmaxf(f.x, f.y), fmaxf(f.z, f.w));
        float nm = fmaxf(m, m4);
        d = d * __expf(m - nm) + __expf(f.x - nm) + __expf(f.y - nm)
          + __expf(f.z - nm) + __expf(f.w - nm);
        m = nm;
    }
    red_m[t] = m; red_d[t] = d; __syncthreads();
    for (int off = 128; off > 0; off >>= 1) {
        if (t < off) {
            float m2 = red_m[t + off], d2 = red_d[t + off];
            float M = fmaxf(red_m[t], m2);
            red_d[t] = red_d[t] * __expf(red_m[t] - M) + d2 * __expf(m2 - M);
            red_m[t] = M;
        }
        __syncthreads();
    }
    float lse = red_m[0] + logf(red_d[0]);
    for (int v = t; v < cV / 4; v += 256) {
        float4 f = row4[v];
        f.x -= lse; f.y -= lse; f.z -= lse; f.w -= lse;
        ((float4*)row)[v] = f;
    }
}

// ---------------------------------------------------------------------------
extern "C" void kernel_launch(void* const* d_in, const int* in_sizes, int n_in,
                              void* d_out, int out_size, void* d_ws, size_t ws_size,
                              hipStream_t stream)
{
    const float* x      = (const float*)d_in[0];
    const float* att    = (const float*)d_in[1];
    const float* prev_c = (const float*)d_in[2];
    const float* prev_h = (const float*)d_in[3];
    const float* W_a2a  = (const float*)d_in[4];
    const float* b_a2a  = (const float*)d_in[5];
    const float* W_h2a  = (const float*)d_in[6];
    const float* b_h2a  = (const float*)d_in[7];
    const float* W_d2d  = (const float*)d_in[8];
    const float* b_d2d  = (const float*)d_in[9];
    const float* W_i2h  = (const float*)d_in[10];
    const float* b_i2h  = (const float*)d_in[11];
    const float* W_a2h  = (const float*)d_in[12];
    const float* b_a2h  = (const float*)d_in[13];
    const float* W_h2h  = (const float*)d_in[14];
    const float* b_h2h  = (const float*)d_in[15];
    const float* W_a2a1 = (const float*)d_in[16];
    const float* b_a2a1 = (const float*)d_in[17];
    const float* W_h2a1 = (const float*)d_in[18];
    const float* b_h2a1 = (const float*)d_in[19];
    const float* W_d2d1 = (const float*)d_in[20];
    const float* b_d2d1 = (const float*)d_in[21];
    const float* W_proj = (const float*)d_in[22];
    const float* b_proj = (const float*)d_in[23];

    float* out_next_c = (float*)d_out;                   // B*R
    float* out_top_h  = out_next_c + (size_t)cB * cR;    // B*R
    float* out_logits = out_top_h  + (size_t)cB * cR;    // B*V

    const size_t ATT_FLOATS = 12845056;   // 25,690,112 bf16
    const size_t AV2_FLOATS = 5017600;    // 50176*200 bf16
    const size_t NEED_A = (ATT_FLOATS + 1445888) * sizeof(float);
    const size_t NEED_B = (ATT_FLOATS + 1445888 + AV2_FLOATS) * sizeof(float);
    bool bigA = ws_size >= NEED_A;
    bool bigB = ws_size >= NEED_B;

    float* ws = (float*)d_ws;
    unsigned short* att_bf = (unsigned short*)ws;         // big paths only
    float* p = bigA ? (ws + ATT_FLOATS) : ws;
    unsigned short* wa2a_bf  = (unsigned short*)p;  p += 50176;
    unsigned short* wa2a1_bf = (unsigned short*)p;  p += 50176;
    unsigned short* x_bf     = (unsigned short*)p;  p += 65536;
    unsigned short* h_bf     = (unsigned short*)p;  p += 65536;
    unsigned short* ar1_bf   = (unsigned short*)p;  p += 65536;
    unsigned short* ar2_bf   = (unsigned short*)p;  p += 65536;
    unsigned short* toph_bf  = (unsigned short*)p;  p += 65536;
    float* ws_ah      = p;  p += 50176;
    float* ws_scores  = p;  p += 50176;
    float* ws_attres1 = p;  p += 131072;
    float* ws_attres2 = p;  p += 131072;
    float* ws_sums    = p;  p += 524288;
    float* ws_next_h  = p;  p += 131072;
    unsigned short* av2 = (unsigned short*)p;             // path B only

    // ---- small bf16 conversions + attend-1 ah, one launch ----
    k_cvt_ah<<<452 + cB, 256, 0, stream>>>(W_a2a, wa2a_bf, 98,
                                           W_a2a1, wa2a1_bf, 98,
                                           x, x_bf, 128,
                                           prev_h, h_bf, 128,
                                           prev_h, W_h2a, b_h2a, ws_ah);

    if (bigB) {
        // ---- merged double-GEMM: scores1 + av2 (+ att bf16 writeback) ----
        k_scores2g<<<(cB * cA) / 128, 512, 0, stream>>>(
            att, att_bf, wa2a_bf, wa2a1_bf, b_a2a, b_a2a1,
            W_d2d, b_d2d, ws_ah, ws_scores, av2);
        k_attres_bf<<<cB, 512, 0, stream>>>(ws_scores, att_bf, nullptr,
                                            ws_attres1, ar1_bf);
        k_sums<<<dim3(8, 32), 256, 0, stream>>>(x_bf, h_bf, ar1_bf,
                                                W_i2h, W_h2h, W_a2h,
                                                b_i2h, b_h2h, b_a2h, ws_sums);
        k_cell_ah<<<cB, 256, 0, stream>>>(ws_sums, prev_c, W_h2a1, b_h2a1,
                                          out_next_c, ws_next_h, ws_ah);
        k_dot2<<<(cB * cA) / 8, 256, 0, stream>>>(av2, ws_ah, W_d2d1, b_d2d1,
                                                  ws_scores);
        k_attres_bf<<<cB, 512, 0, stream>>>(ws_scores, att_bf, ws_next_h,
                                            out_top_h, toph_bf);
    } else if (bigA) {
        // ---- R4 path ----
        k_scores_cv<<<(cB * cA) / 128, 256, 0, stream>>>(att, att_bf, wa2a_bf,
                                                         b_a2a, W_d2d, b_d2d,
                                                         ws_ah, ws_scores, 1);
        k_attres_bf<<<cB, 512, 0, stream>>>(ws_scores, att_bf, nullptr,
                                            ws_attres1, ar1_bf);
        k_sums<<<dim3(8, 32), 256, 0, stream>>>(x_bf, h_bf, ar1_bf,
                                                W_i2h, W_h2h, W_a2h,
                                                b_i2h, b_h2h, b_a2h, ws_sums);
        k_cell_ah<<<cB, 256, 0, stream>>>(ws_sums, prev_c, W_h2a1, b_h2a1,
                                          out_next_c, ws_next_h, ws_ah);
        k_scores_bf<<<(cB * cA) / 128, 256, 0, stream>>>(att_bf, wa2a1_bf,
                                                         b_a2a1, W_d2d1, b_d2d1,
                                                         ws_ah, ws_scores);
        k_attres_bf<<<cB, 512, 0, stream>>>(ws_scores, att_bf, ws_next_h,
                                            out_top_h, toph_bf);
    } else {
        // ---- small-ws fallback: fp32 att path ----
        k_scores_cv<<<(cB * cA) / 128, 256, 0, stream>>>(att, att_bf, wa2a_bf,
                                                         b_a2a, W_d2d, b_d2d,
                                                         ws_ah, ws_scores, 0);
        k_attres_f32<<<cB, 256, 0, stream>>>(ws_scores, att, nullptr,
                                             ws_attres1, ar1_bf);
        k_sums<<<dim3(8, 32), 256, 0, stream>>>(x_bf, h_bf, ar1_bf,
                                                W_i2h, W_h2h, W_a2h,
                                                b_i2h, b_h2h, b_a2h, ws_sums);
        k_cell<<<(cB * cR) / 256, 256, 0, stream>>>(ws_sums, prev_c,
                                                    out_next_c, ws_next_h);
        k_ah<<<cB, 256, 0, stream>>>(ws_next_h, W_h2a1, b_h2a1, ws_ah);
        k_scores_cv<<<(cB * cA) / 128, 256, 0, stream>>>(att, att_bf, wa2a1_bf,
                                                         b_a2a1, W_d2d1, b_d2d1,
                                                         ws_ah, ws_scores, 0);
        k_attres_f32<<<cB, 256, 0, stream>>>(ws_scores, att, ws_next_h,
                                             out_top_h, toph_bf);
    }

    // ---- projection + log_softmax ----
    k_lin<<<dim3(2, 157), 256, 0, stream>>>(toph_bf, W_proj, b_proj, out_logits, cV);
    k_logsoftmax<<<cB, 256, 0, stream>>>(out_logits);
}